// Round 13
// baseline (170.628 us; speedup 1.0000x reference)
//
#include <hip/hip_runtime.h>

typedef unsigned short u16;
typedef unsigned int   u32;

typedef __bf16 bf16x8 __attribute__((ext_vector_type(8)));
typedef float  f32x4  __attribute__((ext_vector_type(4)));

typedef const __attribute__((address_space(1))) void* gas_ptr;
typedef __attribute__((address_space(3))) void* las_ptr;

__device__ __forceinline__ u16 f2bf(float f) {
  u32 u = __builtin_bit_cast(u32, f);
  u += 0x7fffu + ((u >> 16) & 1u);
  return (u16)(u >> 16);
}
__device__ __forceinline__ float bf2f(u16 u) {
  return __builtin_bit_cast(float, ((u32)u) << 16);
}
// packed f32->bf16x2 hardware convert (RTNE), 1 VALU op per pair
__device__ __forceinline__ u32 cvtpk(float a, float b) {
  u32 r;
  asm("v_cvt_pk_bf16_f32 %0, %1, %2" : "=v"(r) : "v"(a), "v"(b));
  return r;
}
// raw v_exp_f32 (2^x, ~1ulp)
__device__ __forceinline__ float fexp2(float x) {
  return __builtin_amdgcn_exp2f(x);
}

// ---------------------------------------------------------------------------
// Kernel 1: BatchNorm over F-channels (stats over B,E) + bf16 cast.
// ---------------------------------------------------------------------------
__global__ __launch_bounds__(256) void bn_norm_kernel(
    const float* __restrict__ x, const float* __restrict__ gamma,
    const float* __restrict__ beta, u16* __restrict__ xn) {
  const int F = 1024, E = 1024;
  int f = blockIdx.x;
  __shared__ float sh[8192];
  __shared__ float ps[4], pq[4], sc[2];

  const float* xf = x + (size_t)f * E;
  float ls = 0.f, lq = 0.f;
  for (int i = threadIdx.x; i < 8192; i += 256) {
    int b = i >> 10, e = i & 1023;
    float v = xf[(size_t)b * F * E + e];
    sh[i] = v;
    ls += v;
    lq += v * v;
  }
  #pragma unroll
  for (int o = 32; o > 0; o >>= 1) {
    ls += __shfl_down(ls, o, 64);
    lq += __shfl_down(lq, o, 64);
  }
  int w = threadIdx.x >> 6;
  if ((threadIdx.x & 63) == 0) { ps[w] = ls; pq[w] = lq; }
  __syncthreads();
  if (threadIdx.x == 0) {
    float s = ps[0] + ps[1] + ps[2] + ps[3];
    float q = pq[0] + pq[1] + pq[2] + pq[3];
    float mean = s * (1.f / 8192.f);
    float var = q * (1.f / 8192.f) - mean * mean;
    float scale = gamma[f] * rsqrtf(var + 1e-5f);
    sc[0] = scale;
    sc[1] = beta[f] - mean * scale;
  }
  __syncthreads();
  float scale = sc[0], shift = sc[1];
  for (int i = threadIdx.x; i < 8192; i += 256) {
    int b = i >> 10, e = i & 1023;
    xn[((size_t)(b * F + f)) * E + e] = f2bf(sh[i] * scale + shift);
  }
}

// ---------------------------------------------------------------------------
// Kernel 2: W_qkv f32 -> bf16
// ---------------------------------------------------------------------------
__global__ __launch_bounds__(256) void wconv_kernel(
    const float* __restrict__ W, u16* __restrict__ Wb) {
  const int total = 3072 * 1024 / 4;
  for (int i = blockIdx.x * 256 + threadIdx.x; i < total; i += gridDim.x * 256) {
    float4 v = ((const float4*)W)[i];
    ushort4 o;
    o.x = f2bf(v.x); o.y = f2bf(v.y); o.z = f2bf(v.z); o.w = f2bf(v.w);
    ((ushort4*)Wb)[i] = o;
  }
}

// ---------------------------------------------------------------------------
// Kernel 3: GEMM v3 — 256x256 tile, BK=64, 8 waves (2Mx4N), 4 phases/K-tile.
//  C[m][n] = sum_k A[m][k]*Bw[n][k] + bias[n]   (bf16 in/out, f32 acc)
//  - double-buffered 128KB LDS; per phase: {ds_read frags | stage 4 loads |
//    s_barrier | lgkmcnt(0)+sched_barrier | setprio(1) 16 MFMA setprio(0) |
//    s_barrier}; staging front-loaded phases 0-1 so the per-tile vmcnt(0)
//    drains ~1500-cy-old loads (no stall).
//  - XOR chunk swizzle (c ^= row&7) source-side for global_load_lds (linear
//    dest) + same XOR on ds_read — 8-cy-floor conflict-free b128 reads.
// ---------------------------------------------------------------------------
__global__ __launch_bounds__(512) void gemm_qkv_kernel(
    const u16* __restrict__ A, const u16* __restrict__ Bw,
    const float* __restrict__ bias, u16* __restrict__ C) {
  const int K = 1024, N = 3072;
  __shared__ u16 LA[2 * 16384];
  __shared__ u16 LB[2 * 16384];

  int bid = blockIdx.x;
  int m0 = (bid & 31) * 256, n0 = (bid >> 5) * 256;

  int tid = threadIdx.x;
  int lane = tid & 63, w = tid >> 6;
  int wm = w >> 2, wn = w & 3;        // 2 x 4 waves
  int q = lane & 15, g = lane >> 4;
  int qs7 = q & 7;

  int srow8 = tid >> 3;               // staging row 0..63 (per 64-row group)
  int sc = tid & 7;                   // staging chunk

  f32x4 acc[8][4] = {};

  #define STAGE_A(buf, t)                                                    \
    do {                                                                     \
      _Pragma("unroll")                                                      \
      for (int j2 = 0; j2 < 4; ++j2) {                                       \
        int row = j2 * 64 + srow8;                                           \
        const u16* src = A + (size_t)(m0 + row) * K + (t) * 64               \
                           + ((sc ^ (row & 7)) * 8);                         \
        __builtin_amdgcn_global_load_lds((gas_ptr)src,                       \
            (las_ptr)&LA[(buf) * 16384 + row * 64 + sc * 8], 16, 0, 0);      \
      }                                                                      \
    } while (0)
  #define STAGE_B(buf, t)                                                    \
    do {                                                                     \
      _Pragma("unroll")                                                      \
      for (int j2 = 0; j2 < 4; ++j2) {                                       \
        int row = j2 * 64 + srow8;                                           \
        const u16* src = Bw + (size_t)(n0 + row) * K + (t) * 64              \
                            + ((sc ^ (row & 7)) * 8);                        \
        __builtin_amdgcn_global_load_lds((gas_ptr)src,                       \
            (las_ptr)&LB[(buf) * 16384 + row * 64 + sc * 8], 16, 0, 0);      \
      }                                                                      \
    } while (0)

  STAGE_A(0, 0);
  STAGE_B(0, 0);
  asm volatile("s_waitcnt vmcnt(0)" ::: "memory");
  __builtin_amdgcn_s_barrier();

  int aBase = (wm * 128 + q) * 64;    // + mi*1024 per 16-row step
  int bBase = (wn * 64 + q) * 64;     // + ni*1024
  int c0 = (g ^ qs7) * 8;             // kk=0 chunk
  int c1 = ((4 + g) ^ qs7) * 8;       // kk=1 chunk

  for (int t = 0; t < 16; ++t) {
    int cur = t & 1, nxt = cur ^ 1;
    const u16* Ab = &LA[cur * 16384];
    const u16* Bb = &LB[cur * 16384];
    bool pf = t < 15;
    bf16x8 Br[4], Ar[4];

    // ---------------- phase 0: Breg(kk0) + A mi0-3(kk0); stage A(t+1)
    #pragma unroll
    for (int ni = 0; ni < 4; ++ni)
      Br[ni] = __builtin_bit_cast(bf16x8, *(const int4*)&Bb[bBase + ni * 1024 + c0]);
    #pragma unroll
    for (int mi = 0; mi < 4; ++mi)
      Ar[mi] = __builtin_bit_cast(bf16x8, *(const int4*)&Ab[aBase + mi * 1024 + c0]);
    if (pf) STAGE_A(nxt, t + 1);
    __builtin_amdgcn_s_barrier();
    asm volatile("s_waitcnt lgkmcnt(0)" ::: "memory");
    __builtin_amdgcn_sched_barrier(0);
    __builtin_amdgcn_s_setprio(1);
    #pragma unroll
    for (int mi = 0; mi < 4; ++mi)
      #pragma unroll
      for (int ni = 0; ni < 4; ++ni)
        acc[mi][ni] = __builtin_amdgcn_mfma_f32_16x16x32_bf16(Ar[mi], Br[ni], acc[mi][ni], 0, 0, 0);
    __builtin_amdgcn_s_setprio(0);
    __builtin_amdgcn_s_barrier();

    // ---------------- phase 1: A mi4-7(kk0); stage B(t+1)
    #pragma unroll
    for (int mi = 0; mi < 4; ++mi)
      Ar[mi] = __builtin_bit_cast(bf16x8, *(const int4*)&Ab[aBase + (4 + mi) * 1024 + c0]);
    if (pf) STAGE_B(nxt, t + 1);
    __builtin_amdgcn_s_barrier();
    asm volatile("s_waitcnt lgkmcnt(0)" ::: "memory");
    __builtin_amdgcn_sched_barrier(0);
    __builtin_amdgcn_s_setprio(1);
    #pragma unroll
    for (int mi = 0; mi < 4; ++mi)
      #pragma unroll
      for (int ni = 0; ni < 4; ++ni)
        acc[4 + mi][ni] = __builtin_amdgcn_mfma_f32_16x16x32_bf16(Ar[mi], Br[ni], acc[4 + mi][ni], 0, 0, 0);
    __builtin_amdgcn_s_setprio(0);
    __builtin_amdgcn_s_barrier();

    // ---------------- phase 2: Breg(kk1) + A mi0-3(kk1)
    #pragma unroll
    for (int ni = 0; ni < 4; ++ni)
      Br[ni] = __builtin_bit_cast(bf16x8, *(const int4*)&Bb[bBase + ni * 1024 + c1]);
    #pragma unroll
    for (int mi = 0; mi < 4; ++mi)
      Ar[mi] = __builtin_bit_cast(bf16x8, *(const int4*)&Ab[aBase + mi * 1024 + c1]);
    __builtin_amdgcn_s_barrier();
    asm volatile("s_waitcnt lgkmcnt(0)" ::: "memory");
    __builtin_amdgcn_sched_barrier(0);
    __builtin_amdgcn_s_setprio(1);
    #pragma unroll
    for (int mi = 0; mi < 4; ++mi)
      #pragma unroll
      for (int ni = 0; ni < 4; ++ni)
        acc[mi][ni] = __builtin_amdgcn_mfma_f32_16x16x32_bf16(Ar[mi], Br[ni], acc[mi][ni], 0, 0, 0);
    __builtin_amdgcn_s_setprio(0);
    __builtin_amdgcn_s_barrier();

    // ---------------- phase 3: A mi4-7(kk1); tile-boundary drain
    #pragma unroll
    for (int mi = 0; mi < 4; ++mi)
      Ar[mi] = __builtin_bit_cast(bf16x8, *(const int4*)&Ab[aBase + (4 + mi) * 1024 + c1]);
    __builtin_amdgcn_s_barrier();
    asm volatile("s_waitcnt lgkmcnt(0)" ::: "memory");
    __builtin_amdgcn_sched_barrier(0);
    __builtin_amdgcn_s_setprio(1);
    #pragma unroll
    for (int mi = 0; mi < 4; ++mi)
      #pragma unroll
      for (int ni = 0; ni < 4; ++ni)
        acc[4 + mi][ni] = __builtin_amdgcn_mfma_f32_16x16x32_bf16(Ar[mi], Br[ni], acc[4 + mi][ni], 0, 0, 0);
    __builtin_amdgcn_s_setprio(0);
    asm volatile("s_waitcnt vmcnt(0)" ::: "memory");
    __builtin_amdgcn_s_barrier();
  }
  #undef STAGE_A
  #undef STAGE_B

  // ---- epilogue: bias + bf16 store (m97-verified C/D mapping)
  #pragma unroll
  for (int ni = 0; ni < 4; ++ni) {
    int col = n0 + wn * 64 + ni * 16 + q;
    float bv = bias[col];
    #pragma unroll
    for (int mi = 0; mi < 8; ++mi) {
      int row = m0 + wm * 128 + mi * 16 + g * 4;
      #pragma unroll
      for (int j = 0; j < 4; ++j)
        C[(size_t)(row + j) * N + col] = f2bf(acc[mi][ni][j] + bv);
    }
  }
}

// ---------------------------------------------------------------------------
// Kernel 3b: V transpose WITH baked key permutation (verified R3).
// ---------------------------------------------------------------------------
__global__ __launch_bounds__(256) void vt_kernel(
    const u16* __restrict__ qkv, u16* __restrict__ Vt) {
  __shared__ u16 T[64][72];
  int bh = blockIdx.y, b = bh >> 4, h = bh & 15;
  int f0 = blockIdx.x * 64;
  int t = threadIdx.x;
  int fl = t >> 2, c16 = (t & 3) * 16;
  const u16* src = qkv + (size_t)(b * 1024 + f0 + fl) * 3072 + h * 192 + 128 + c16;
  *(int4*)&T[fl][c16]     = *(const int4*)src;
  *(int4*)&T[fl][c16 + 8] = *(const int4*)(src + 8);
  __syncthreads();
  int dl = t >> 2, fc = (t & 3) * 16;
  u16 buf[16];
  #pragma unroll
  for (int j = 0; j < 16; ++j) {
    int c = fc + j;
    int m = c & 31;
    int a = ((m & 4) << 2) | ((m & 16) >> 1) | ((m & 8) >> 1) | (m & 3);
    buf[j] = T[(c & 32) | a][dl];
  }
  u16* dst = Vt + (size_t)bh * 65536 + (size_t)dl * 1024 + f0 + fc;
  *(int4*)dst       = *(int4*)&buf[0];
  *(int4*)(dst + 8) = *(int4*)&buf[8];
}

// ---------------------------------------------------------------------------
// Kernel 4: flash attention v9 (R12 winner, 69.6us) — raw v_exp, full unroll,
// triple-buffered K/V, counted-vmcnt pipeline, seeded-C softmax.
// ---------------------------------------------------------------------------
__global__ __launch_bounds__(256) void attn_kernel(
    const u16* __restrict__ qkv, const u16* __restrict__ Vt,
    float* __restrict__ out) {
  const int F = 1024, NQ = 3072;
  int bid = blockIdx.x;           // 2048 blocks
  int xcd = bid & 7;
  int li  = bid >> 3;             // 0..255
  int bh  = ((li >> 4) << 3) | xcd;
  int ql  = li & 15;
  int w   = threadIdx.x >> 6;
  int lane = threadIdx.x & 63;
  int q = lane & 15, g = lane >> 4;
  int qs = q & 7;
  int q0 = ql * 64 + w * 16;
  int b = bh >> 4, h = bh & 15;

  const u16* base = qkv + (size_t)b * F * NQ + h * 192;
  const u16* VtBH = Vt + (size_t)bh * 65536;

  __shared__ u16 S[24576];

  int i8 = lane >> 3;
  int ic = lane & 7;

  const float qscale = 0.125f * 1.4426950408889634f;
  bf16x8 Qf0, Qf1;
  {
    const u16* qp = base + (size_t)(q0 + q) * NQ + g * 8;
    union { int4 v; u16 u[8]; } uu0, uu1;
    uu0.v = *(const int4*)(qp);
    uu1.v = *(const int4*)(qp + 32);
    union { u32 w4[4]; bf16x8 v; } p0, p1;
    #pragma unroll
    for (int j = 0; j < 4; ++j) {
      p0.w4[j] = cvtpk(bf2f(uu0.u[2 * j]) * qscale, bf2f(uu0.u[2 * j + 1]) * qscale);
      p1.w4[j] = cvtpk(bf2f(uu1.u[2 * j]) * qscale, bf2f(uu1.u[2 * j + 1]) * qscale);
    }
    Qf0 = p0.v; Qf1 = p1.v;
  }

  f32x4 acc[4] = {};
  float m = 0.0f, lsum = 0.f;

  #define STAGE(buf, kt)                                                       \
    do {                                                                       \
      int kb_ = (kt) * 64;                                                     \
      _Pragma("unroll")                                                        \
      for (int rr = 0; rr < 2; ++rr) {                                         \
        int r_ = rr * 32 + w * 8 + i8;                                         \
        int sc_ = (ic ^ (r_ & 7)) * 8;                                         \
        const u16* ks_ = base + (size_t)(kb_ + r_) * NQ + 64 + sc_;            \
        const u16* vs_ = VtBH + (size_t)r_ * 1024 + kb_ + sc_;                 \
        __builtin_amdgcn_global_load_lds((gas_ptr)ks_,                         \
            (las_ptr)&S[(buf) * 4096 + (rr * 32 + w * 8) * 64], 16, 0, 0);     \
        __builtin_amdgcn_global_load_lds((gas_ptr)vs_,                         \
            (las_ptr)&S[12288 + (buf) * 4096 + (rr * 32 + w * 8) * 64], 16, 0, 0);\
      }                                                                        \
    } while (0)

  __builtin_amdgcn_sched_barrier(0);
  STAGE(0, 0);
  STAGE(1, 1);
  asm volatile("s_waitcnt vmcnt(4)" ::: "memory");
  __builtin_amdgcn_s_barrier();
  __builtin_amdgcn_sched_barrier(0);

  #pragma unroll
  for (int kt = 0; kt < 16; ++kt) {
    const int cur = kt % 3;
    const int stg = (kt + 2) % 3;
    if (kt < 14) STAGE(stg, kt + 2);

    const u16* Kb = &S[cur * 4096];
    const u16* Vb = &S[12288 + cur * 4096];

    f32x4 s[4];
    f32x4 seed = {-m, -m, -m, -m};
    __builtin_amdgcn_s_setprio(1);
    #pragma unroll
    for (int ks = 0; ks < 4; ++ks) {
      int row = ks * 16 + q;
      int4 k0 = *(const int4*)&Kb[row * 64 + ((g ^ qs) * 8)];
      int4 k1 = *(const int4*)&Kb[row * 64 + (((4 + g) ^ qs) * 8)];
      f32x4 sv = seed;
      sv = __builtin_amdgcn_mfma_f32_16x16x32_bf16(__builtin_bit_cast(bf16x8, k0), Qf0, sv, 0, 0, 0);
      sv = __builtin_amdgcn_mfma_f32_16x16x32_bf16(__builtin_bit_cast(bf16x8, k1), Qf1, sv, 0, 0, 0);
      s[ks] = sv;
    }
    __builtin_amdgcn_s_setprio(0);

    float a0 = fmaxf(fmaxf(s[0][0], s[0][1]), s[0][2]);
    float a1 = fmaxf(fmaxf(s[0][3], s[1][0]), s[1][1]);
    float a2 = fmaxf(fmaxf(s[1][2], s[1][3]), s[2][0]);
    float a3 = fmaxf(fmaxf(s[2][1], s[2][2]), s[2][3]);
    float a4 = fmaxf(fmaxf(s[3][0], s[3][1]), s[3][2]);
    float tmx = fmaxf(fmaxf(fmaxf(a0, a1), a2), fmaxf(fmaxf(a3, a4), s[3][3]));

    float p[16];
    if (__builtin_expect(__any(tmx > 8.0f), 0)) {
      float tr = fmaxf(tmx, __shfl_xor(tmx, 16, 64));
      tr = fmaxf(tr, __shfl_xor(tr, 32, 64));
      float dm = fmaxf(tr, 0.f);
      float alpha = fexp2(-dm);
      lsum *= alpha;
      acc[0] *= alpha; acc[1] *= alpha; acc[2] *= alpha; acc[3] *= alpha;
      m += dm;
      #pragma unroll
      for (int ks = 0; ks < 4; ++ks) {
        p[ks * 4 + 0] = fexp2(s[ks][0] - dm);
        p[ks * 4 + 1] = fexp2(s[ks][1] - dm);
        p[ks * 4 + 2] = fexp2(s[ks][2] - dm);
        p[ks * 4 + 3] = fexp2(s[ks][3] - dm);
      }
    } else {
      #pragma unroll
      for (int ks = 0; ks < 4; ++ks) {
        p[ks * 4 + 0] = fexp2(s[ks][0]);
        p[ks * 4 + 1] = fexp2(s[ks][1]);
        p[ks * 4 + 2] = fexp2(s[ks][2]);
        p[ks * 4 + 3] = fexp2(s[ks][3]);
      }
    }
    float q01 = p[0] + p[1],   q23 = p[2] + p[3];
    float q45 = p[4] + p[5],   q67 = p[6] + p[7];
    float q89 = p[8] + p[9],   qab = p[10] + p[11];
    float qcd = p[12] + p[13], qef = p[14] + p[15];
    lsum += ((q01 + q23) + (q45 + q67)) + ((q89 + qab) + (qcd + qef));

    union { u32 w4[4]; bf16x8 v; } pb0, pb1;
    pb0.w4[0] = cvtpk(p[0], p[1]);   pb0.w4[1] = cvtpk(p[2], p[3]);
    pb0.w4[2] = cvtpk(p[4], p[5]);   pb0.w4[3] = cvtpk(p[6], p[7]);
    pb1.w4[0] = cvtpk(p[8], p[9]);   pb1.w4[1] = cvtpk(p[10], p[11]);
    pb1.w4[2] = cvtpk(p[12], p[13]); pb1.w4[3] = cvtpk(p[14], p[15]);

    __builtin_amdgcn_s_setprio(1);
    #pragma unroll
    for (int dt = 0; dt < 4; ++dt) {
      int row = dt * 16 + q;
      int4 v0 = *(const int4*)&Vb[row * 64 + ((g ^ qs) * 8)];
      int4 v1 = *(const int4*)&Vb[row * 64 + (((4 + g) ^ qs) * 8)];
      acc[dt] = __builtin_amdgcn_mfma_f32_16x16x32_bf16(__builtin_bit_cast(bf16x8, v0), pb0.v, acc[dt], 0, 0, 0);
      acc[dt] = __builtin_amdgcn_mfma_f32_16x16x32_bf16(__builtin_bit_cast(bf16x8, v1), pb1.v, acc[dt], 0, 0, 0);
    }
    __builtin_amdgcn_s_setprio(0);

    if (kt < 14) {
      asm volatile("s_waitcnt vmcnt(4)" ::: "memory");
    } else {
      asm volatile("s_waitcnt vmcnt(0)" ::: "memory");
    }
    __builtin_amdgcn_s_barrier();
    __builtin_amdgcn_sched_barrier(0);
  }
  #undef STAGE

  lsum += __shfl_xor(lsum, 16, 64);
  lsum += __shfl_xor(lsum, 32, 64);
  float inv = 1.0f / lsum;

  float* oT = (float*)S + (size_t)w * 1088;
  #pragma unroll
  for (int dt = 0; dt < 4; ++dt) {
    oT[(dt * 16 + g * 4 + 0) * 17 + q] = acc[dt][0] * inv;
    oT[(dt * 16 + g * 4 + 1) * 17 + q] = acc[dt][1] * inv;
    oT[(dt * 16 + g * 4 + 2) * 17 + q] = acc[dt][2] * inv;
    oT[(dt * 16 + g * 4 + 3) * 17 + q] = acc[dt][3] * inv;
  }
  asm volatile("s_waitcnt lgkmcnt(0)" ::: "memory");
  int oq = lane >> 2, dc = (lane & 3) * 16;
  float* orow = out + (size_t)(b * F + q0 + oq) * 1024 + h * 64 + dc;
  #pragma unroll
  for (int c4 = 0; c4 < 4; ++c4) {
    float4 v;
    v.x = oT[(dc + c4 * 4 + 0) * 17 + oq];
    v.y = oT[(dc + c4 * 4 + 1) * 17 + oq];
    v.z = oT[(dc + c4 * 4 + 2) * 17 + oq];
    v.w = oT[(dc + c4 * 4 + 3) * 17 + oq];
    *(float4*)(orow + c4 * 4) = v;
  }
}

// ---------------------------------------------------------------------------
extern "C" void kernel_launch(void* const* d_in, const int* in_sizes, int n_in,
                              void* d_out, int out_size, void* d_ws, size_t ws_size,
                              hipStream_t stream) {
  const float* x     = (const float*)d_in[0];
  const float* gamma = (const float*)d_in[1];
  const float* beta  = (const float*)d_in[2];
  const float* W     = (const float*)d_in[3];
  const float* bias  = (const float*)d_in[4];
  float* out = (float*)d_out;

  char* ws = (char*)d_ws;
  u16* xn  = (u16*)ws;                                   // 16 MB
  u16* Wb  = (u16*)(ws + (size_t)16 * 1024 * 1024);      //  6 MB
  u16* qkv = (u16*)(ws + (size_t)22 * 1024 * 1024);      // 48 MB
  u16* Vt  = (u16*)(ws + (size_t)70 * 1024 * 1024);      // 16 MB

  bn_norm_kernel<<<1024, 256, 0, stream>>>(x, gamma, beta, xn);
  wconv_kernel<<<768, 256, 0, stream>>>(W, Wb);
  gemm_qkv_kernel<<<384, 512, 0, stream>>>(xn, Wb, bias, qkv);
  vt_kernel<<<dim3(16, 128), 256, 0, stream>>>(qkv, Vt);
  attn_kernel<<<2048, 256, 0, stream>>>(qkv, Vt, out);
}

// Round 14
// 164.095 us; speedup vs baseline: 1.0398x; 1.0398x over previous
//
#include <hip/hip_runtime.h>

typedef unsigned short u16;
typedef unsigned int   u32;

typedef __bf16 bf16x8 __attribute__((ext_vector_type(8)));
typedef float  f32x4  __attribute__((ext_vector_type(4)));

typedef const __attribute__((address_space(1))) void* gas_ptr;
typedef __attribute__((address_space(3))) void* las_ptr;

__device__ __forceinline__ u16 f2bf(float f) {
  u32 u = __builtin_bit_cast(u32, f);
  u += 0x7fffu + ((u >> 16) & 1u);
  return (u16)(u >> 16);
}
__device__ __forceinline__ float bf2f(u16 u) {
  return __builtin_bit_cast(float, ((u32)u) << 16);
}
// packed f32->bf16x2 hardware convert (RTNE), 1 VALU op per pair
__device__ __forceinline__ u32 cvtpk(float a, float b) {
  u32 r;
  asm("v_cvt_pk_bf16_f32 %0, %1, %2" : "=v"(r) : "v"(a), "v"(b));
  return r;
}
// raw v_exp_f32 (2^x, ~1ulp)
__device__ __forceinline__ float fexp2(float x) {
  return __builtin_amdgcn_exp2f(x);
}

// ---------------------------------------------------------------------------
// Kernel 1: BatchNorm over F-channels (stats over B,E) + bf16 cast.
// ---------------------------------------------------------------------------
__global__ __launch_bounds__(256) void bn_norm_kernel(
    const float* __restrict__ x, const float* __restrict__ gamma,
    const float* __restrict__ beta, u16* __restrict__ xn) {
  const int F = 1024, E = 1024;
  int f = blockIdx.x;
  __shared__ float sh[8192];
  __shared__ float ps[4], pq[4], sc[2];

  const float* xf = x + (size_t)f * E;
  float ls = 0.f, lq = 0.f;
  for (int i = threadIdx.x; i < 8192; i += 256) {
    int b = i >> 10, e = i & 1023;
    float v = xf[(size_t)b * F * E + e];
    sh[i] = v;
    ls += v;
    lq += v * v;
  }
  #pragma unroll
  for (int o = 32; o > 0; o >>= 1) {
    ls += __shfl_down(ls, o, 64);
    lq += __shfl_down(lq, o, 64);
  }
  int w = threadIdx.x >> 6;
  if ((threadIdx.x & 63) == 0) { ps[w] = ls; pq[w] = lq; }
  __syncthreads();
  if (threadIdx.x == 0) {
    float s = ps[0] + ps[1] + ps[2] + ps[3];
    float q = pq[0] + pq[1] + pq[2] + pq[3];
    float mean = s * (1.f / 8192.f);
    float var = q * (1.f / 8192.f) - mean * mean;
    float scale = gamma[f] * rsqrtf(var + 1e-5f);
    sc[0] = scale;
    sc[1] = beta[f] - mean * scale;
  }
  __syncthreads();
  float scale = sc[0], shift = sc[1];
  for (int i = threadIdx.x; i < 8192; i += 256) {
    int b = i >> 10, e = i & 1023;
    xn[((size_t)(b * F + f)) * E + e] = f2bf(sh[i] * scale + shift);
  }
}

// ---------------------------------------------------------------------------
// Kernel 2: W_qkv f32 -> bf16
// ---------------------------------------------------------------------------
__global__ __launch_bounds__(256) void wconv_kernel(
    const float* __restrict__ W, u16* __restrict__ Wb) {
  const int total = 3072 * 1024 / 4;
  for (int i = blockIdx.x * 256 + threadIdx.x; i < total; i += gridDim.x * 256) {
    float4 v = ((const float4*)W)[i];
    ushort4 o;
    o.x = f2bf(v.x); o.y = f2bf(v.y); o.z = f2bf(v.z); o.w = f2bf(v.w);
    ((ushort4*)Wb)[i] = o;
  }
}

// ---------------------------------------------------------------------------
// Kernel 3: GEMM v4 — 256x256, BK=64 split into K-halves, m201 phase rhythm.
//  - LDS 128KB: A[slot][half] 4x16KB + B[slot][half] 4x16KB (half = 32 k-cols).
//  - per phase: {8 ds_read | stage ONE half-operand (2 loads) | barrier |
//    lgkmcnt(0)+sched_barrier | setprio(1) 16 MFMA setprio(0) | barrier}.
//  - stage targets freed exactly 2 phases earlier (race-free by barrier
//    timeline); counted vmcnt(8) at phase-1/3 ends only (never 0 mid-loop).
//  - swizzle: chunk ^= (row>>1)&3 source-side, same XOR on ds_read.
// ---------------------------------------------------------------------------
__global__ __launch_bounds__(512) void gemm_qkv_kernel(
    const u16* __restrict__ A, const u16* __restrict__ Bw,
    const float* __restrict__ bias, u16* __restrict__ C) {
  const int K = 1024, N = 3072;
  __shared__ u16 LS[65536];   // A: [0,32768) ; B: [32768,65536)

  int li = (blockIdx.x & 7) * 48 + (blockIdx.x >> 3);   // XCD-chunked, 384%8==0
  int m0 = (li & 31) * 256, n0 = (li >> 5) * 256;

  int tid = threadIdx.x;
  int lane = tid & 63, w = tid >> 6;
  int wm = w >> 2, wn = w & 3;        // 2 x 4 waves
  int q = lane & 15, g = lane >> 4;
  int qh = (q >> 1) & 3;
  int cfr = (g ^ qh) * 8;             // fragment chunk offset (u16)

  f32x4 acc[8][4] = {};

  // stage one half (A or B) of tile t into slot/half region
  #define STAGE_A(slot, h, t)                                                  \
    do {                                                                       \
      _Pragma("unroll")                                                        \
      for (int j = 0; j < 2; ++j) {                                            \
        int row = j * 128 + (tid >> 2);                                        \
        int cc = (tid & 3) ^ ((row >> 1) & 3);                                 \
        const u16* src = A + (size_t)(m0 + row) * K + (t) * 64 + (h) * 32 + cc * 8; \
        __builtin_amdgcn_global_load_lds((gas_ptr)src,                         \
            (las_ptr)&LS[(slot) * 16384 + (h) * 8192 + j * 4096 + tid * 8], 16, 0, 0); \
      }                                                                        \
    } while (0)
  #define STAGE_B(slot, h, t)                                                  \
    do {                                                                       \
      _Pragma("unroll")                                                        \
      for (int j = 0; j < 2; ++j) {                                            \
        int row = j * 128 + (tid >> 2);                                        \
        int cc = (tid & 3) ^ ((row >> 1) & 3);                                 \
        const u16* src = Bw + (size_t)(n0 + row) * K + (t) * 64 + (h) * 32 + cc * 8; \
        __builtin_amdgcn_global_load_lds((gas_ptr)src,                         \
            (las_ptr)&LS[32768 + (slot) * 16384 + (h) * 8192 + j * 4096 + tid * 8], 16, 0, 0); \
      }                                                                        \
    } while (0)

  // prologue: tile0 (both halves) + tile1 half0; wait only tile0-h0 (8 newer)
  STAGE_A(0, 0, 0); STAGE_B(0, 0, 0);
  STAGE_A(0, 1, 0); STAGE_B(0, 1, 0);
  STAGE_A(1, 0, 1); STAGE_B(1, 0, 1);
  asm volatile("s_waitcnt vmcnt(8)" ::: "memory");
  __builtin_amdgcn_s_barrier();

  for (int kt = 0; kt < 16; ++kt) {
    int d = kt & 1, dn = (kt + 1) & 1;
    const u16* Ab0 = &LS[d * 16384];
    const u16* Bb0 = &LS[32768 + d * 16384];
    const u16* Ab1 = Ab0 + 8192;
    const u16* Bb1 = Bb0 + 8192;
    int aOff = (wm * 128 + q) * 32 + cfr;   // + mi*512 per 16-row step
    int bOff = (wn * 64 + q) * 32 + cfr;    // + ni*512

    bf16x8 Ar[4], Br[4];

    // ========== ph0: Br(h0), Ar mi0-3(h0); stage A-h1(kt+1)
    #pragma unroll
    for (int ni = 0; ni < 4; ++ni)
      Br[ni] = __builtin_bit_cast(bf16x8, *(const int4*)&Bb0[bOff + ni * 512]);
    #pragma unroll
    for (int mi = 0; mi < 4; ++mi)
      Ar[mi] = __builtin_bit_cast(bf16x8, *(const int4*)&Ab0[aOff + mi * 512]);
    if (kt < 15) STAGE_A(dn, 1, kt + 1);
    __builtin_amdgcn_s_barrier();
    asm volatile("s_waitcnt lgkmcnt(0)" ::: "memory");
    __builtin_amdgcn_sched_barrier(0);
    __builtin_amdgcn_s_setprio(1);
    #pragma unroll
    for (int mi = 0; mi < 4; ++mi)
      #pragma unroll
      for (int ni = 0; ni < 4; ++ni)
        acc[mi][ni] = __builtin_amdgcn_mfma_f32_16x16x32_bf16(Ar[mi], Br[ni], acc[mi][ni], 0, 0, 0);
    __builtin_amdgcn_s_setprio(0);
    __builtin_amdgcn_s_barrier();

    // ========== ph1: Ar mi4-7(h0); stage B-h1(kt+1); ckpt vmcnt(8)
    #pragma unroll
    for (int mi = 0; mi < 4; ++mi)
      Ar[mi] = __builtin_bit_cast(bf16x8, *(const int4*)&Ab0[aOff + (4 + mi) * 512]);
    if (kt < 15) STAGE_B(dn, 1, kt + 1);
    __builtin_amdgcn_s_barrier();
    asm volatile("s_waitcnt lgkmcnt(0)" ::: "memory");
    __builtin_amdgcn_sched_barrier(0);
    __builtin_amdgcn_s_setprio(1);
    #pragma unroll
    for (int mi = 0; mi < 4; ++mi)
      #pragma unroll
      for (int ni = 0; ni < 4; ++ni)
        acc[4 + mi][ni] = __builtin_amdgcn_mfma_f32_16x16x32_bf16(Ar[mi], Br[ni], acc[4 + mi][ni], 0, 0, 0);
    __builtin_amdgcn_s_setprio(0);
    if (kt < 15) { asm volatile("s_waitcnt vmcnt(8)" ::: "memory"); }
    else         { asm volatile("s_waitcnt vmcnt(0)" ::: "memory"); }
    __builtin_amdgcn_s_barrier();

    // ========== ph2: Br(h1), Ar mi0-3(h1); stage A-h0(kt+2)
    #pragma unroll
    for (int ni = 0; ni < 4; ++ni)
      Br[ni] = __builtin_bit_cast(bf16x8, *(const int4*)&Bb1[bOff + ni * 512]);
    #pragma unroll
    for (int mi = 0; mi < 4; ++mi)
      Ar[mi] = __builtin_bit_cast(bf16x8, *(const int4*)&Ab1[aOff + mi * 512]);
    if (kt < 14) STAGE_A(d, 0, kt + 2);
    __builtin_amdgcn_s_barrier();
    asm volatile("s_waitcnt lgkmcnt(0)" ::: "memory");
    __builtin_amdgcn_sched_barrier(0);
    __builtin_amdgcn_s_setprio(1);
    #pragma unroll
    for (int mi = 0; mi < 4; ++mi)
      #pragma unroll
      for (int ni = 0; ni < 4; ++ni)
        acc[mi][ni] = __builtin_amdgcn_mfma_f32_16x16x32_bf16(Ar[mi], Br[ni], acc[mi][ni], 0, 0, 0);
    __builtin_amdgcn_s_setprio(0);
    __builtin_amdgcn_s_barrier();

    // ========== ph3: Ar mi4-7(h1); stage B-h0(kt+2); ckpt
    #pragma unroll
    for (int mi = 0; mi < 4; ++mi)
      Ar[mi] = __builtin_bit_cast(bf16x8, *(const int4*)&Ab1[aOff + (4 + mi) * 512]);
    if (kt < 14) STAGE_B(d, 0, kt + 2);
    __builtin_amdgcn_s_barrier();
    asm volatile("s_waitcnt lgkmcnt(0)" ::: "memory");
    __builtin_amdgcn_sched_barrier(0);
    __builtin_amdgcn_s_setprio(1);
    #pragma unroll
    for (int mi = 0; mi < 4; ++mi)
      #pragma unroll
      for (int ni = 0; ni < 4; ++ni)
        acc[4 + mi][ni] = __builtin_amdgcn_mfma_f32_16x16x32_bf16(Ar[mi], Br[ni], acc[4 + mi][ni], 0, 0, 0);
    __builtin_amdgcn_s_setprio(0);
    if (kt < 14)      { asm volatile("s_waitcnt vmcnt(8)" ::: "memory"); }
    else if (kt == 14){ asm volatile("s_waitcnt vmcnt(4)" ::: "memory"); }
    else              { asm volatile("s_waitcnt vmcnt(0)" ::: "memory"); }
    __builtin_amdgcn_s_barrier();
  }
  #undef STAGE_A
  #undef STAGE_B

  // ---- epilogue: bias + bf16 store (mapping verified R13)
  #pragma unroll
  for (int ni = 0; ni < 4; ++ni) {
    int col = n0 + wn * 64 + ni * 16 + q;
    float bv = bias[col];
    #pragma unroll
    for (int mi = 0; mi < 8; ++mi) {
      int row = m0 + wm * 128 + mi * 16 + g * 4;
      #pragma unroll
      for (int j = 0; j < 4; ++j)
        C[(size_t)(row + j) * N + col] = f2bf(acc[mi][ni][j] + bv);
    }
  }
}

// ---------------------------------------------------------------------------
// Kernel 3b: V transpose WITH baked key permutation (verified R3).
// ---------------------------------------------------------------------------
__global__ __launch_bounds__(256) void vt_kernel(
    const u16* __restrict__ qkv, u16* __restrict__ Vt) {
  __shared__ u16 T[64][72];
  int bh = blockIdx.y, b = bh >> 4, h = bh & 15;
  int f0 = blockIdx.x * 64;
  int t = threadIdx.x;
  int fl = t >> 2, c16 = (t & 3) * 16;
  const u16* src = qkv + (size_t)(b * 1024 + f0 + fl) * 3072 + h * 192 + 128 + c16;
  *(int4*)&T[fl][c16]     = *(const int4*)src;
  *(int4*)&T[fl][c16 + 8] = *(const int4*)(src + 8);
  __syncthreads();
  int dl = t >> 2, fc = (t & 3) * 16;
  u16 buf[16];
  #pragma unroll
  for (int j = 0; j < 16; ++j) {
    int c = fc + j;
    int m = c & 31;
    int a = ((m & 4) << 2) | ((m & 16) >> 1) | ((m & 8) >> 1) | (m & 3);
    buf[j] = T[(c & 32) | a][dl];
  }
  u16* dst = Vt + (size_t)bh * 65536 + (size_t)dl * 1024 + f0 + fc;
  *(int4*)dst       = *(int4*)&buf[0];
  *(int4*)(dst + 8) = *(int4*)&buf[8];
}

// ---------------------------------------------------------------------------
// Kernel 4: flash attention v9 (R12 winner, 69.6us) — raw v_exp, full unroll,
// triple-buffered K/V, counted-vmcnt pipeline, seeded-C softmax.
// ---------------------------------------------------------------------------
__global__ __launch_bounds__(256) void attn_kernel(
    const u16* __restrict__ qkv, const u16* __restrict__ Vt,
    float* __restrict__ out) {
  const int F = 1024, NQ = 3072;
  int bid = blockIdx.x;           // 2048 blocks
  int xcd = bid & 7;
  int li  = bid >> 3;             // 0..255
  int bh  = ((li >> 4) << 3) | xcd;
  int ql  = li & 15;
  int w   = threadIdx.x >> 6;
  int lane = threadIdx.x & 63;
  int q = lane & 15, g = lane >> 4;
  int qs = q & 7;
  int q0 = ql * 64 + w * 16;
  int b = bh >> 4, h = bh & 15;

  const u16* base = qkv + (size_t)b * F * NQ + h * 192;
  const u16* VtBH = Vt + (size_t)bh * 65536;

  __shared__ u16 S[24576];

  int i8 = lane >> 3;
  int ic = lane & 7;

  const float qscale = 0.125f * 1.4426950408889634f;
  bf16x8 Qf0, Qf1;
  {
    const u16* qp = base + (size_t)(q0 + q) * NQ + g * 8;
    union { int4 v; u16 u[8]; } uu0, uu1;
    uu0.v = *(const int4*)(qp);
    uu1.v = *(const int4*)(qp + 32);
    union { u32 w4[4]; bf16x8 v; } p0, p1;
    #pragma unroll
    for (int j = 0; j < 4; ++j) {
      p0.w4[j] = cvtpk(bf2f(uu0.u[2 * j]) * qscale, bf2f(uu0.u[2 * j + 1]) * qscale);
      p1.w4[j] = cvtpk(bf2f(uu1.u[2 * j]) * qscale, bf2f(uu1.u[2 * j + 1]) * qscale);
    }
    Qf0 = p0.v; Qf1 = p1.v;
  }

  f32x4 acc[4] = {};
  float m = 0.0f, lsum = 0.f;

  #define STAGE(buf, kt)                                                       \
    do {                                                                       \
      int kb_ = (kt) * 64;                                                     \
      _Pragma("unroll")                                                        \
      for (int rr = 0; rr < 2; ++rr) {                                         \
        int r_ = rr * 32 + w * 8 + i8;                                         \
        int sc_ = (ic ^ (r_ & 7)) * 8;                                         \
        const u16* ks_ = base + (size_t)(kb_ + r_) * NQ + 64 + sc_;            \
        const u16* vs_ = VtBH + (size_t)r_ * 1024 + kb_ + sc_;                 \
        __builtin_amdgcn_global_load_lds((gas_ptr)ks_,                         \
            (las_ptr)&S[(buf) * 4096 + (rr * 32 + w * 8) * 64], 16, 0, 0);     \
        __builtin_amdgcn_global_load_lds((gas_ptr)vs_,                         \
            (las_ptr)&S[12288 + (buf) * 4096 + (rr * 32 + w * 8) * 64], 16, 0, 0);\
      }                                                                        \
    } while (0)

  __builtin_amdgcn_sched_barrier(0);
  STAGE(0, 0);
  STAGE(1, 1);
  asm volatile("s_waitcnt vmcnt(4)" ::: "memory");
  __builtin_amdgcn_s_barrier();
  __builtin_amdgcn_sched_barrier(0);

  #pragma unroll
  for (int kt = 0; kt < 16; ++kt) {
    const int cur = kt % 3;
    const int stg = (kt + 2) % 3;
    if (kt < 14) STAGE(stg, kt + 2);

    const u16* Kb = &S[cur * 4096];
    const u16* Vb = &S[12288 + cur * 4096];

    f32x4 s[4];
    f32x4 seed = {-m, -m, -m, -m};
    __builtin_amdgcn_s_setprio(1);
    #pragma unroll
    for (int ks = 0; ks < 4; ++ks) {
      int row = ks * 16 + q;
      int4 k0 = *(const int4*)&Kb[row * 64 + ((g ^ qs) * 8)];
      int4 k1 = *(const int4*)&Kb[row * 64 + (((4 + g) ^ qs) * 8)];
      f32x4 sv = seed;
      sv = __builtin_amdgcn_mfma_f32_16x16x32_bf16(__builtin_bit_cast(bf16x8, k0), Qf0, sv, 0, 0, 0);
      sv = __builtin_amdgcn_mfma_f32_16x16x32_bf16(__builtin_bit_cast(bf16x8, k1), Qf1, sv, 0, 0, 0);
      s[ks] = sv;
    }
    __builtin_amdgcn_s_setprio(0);

    float a0 = fmaxf(fmaxf(s[0][0], s[0][1]), s[0][2]);
    float a1 = fmaxf(fmaxf(s[0][3], s[1][0]), s[1][1]);
    float a2 = fmaxf(fmaxf(s[1][2], s[1][3]), s[2][0]);
    float a3 = fmaxf(fmaxf(s[2][1], s[2][2]), s[2][3]);
    float a4 = fmaxf(fmaxf(s[3][0], s[3][1]), s[3][2]);
    float tmx = fmaxf(fmaxf(fmaxf(a0, a1), a2), fmaxf(fmaxf(a3, a4), s[3][3]));

    float p[16];
    if (__builtin_expect(__any(tmx > 8.0f), 0)) {
      float tr = fmaxf(tmx, __shfl_xor(tmx, 16, 64));
      tr = fmaxf(tr, __shfl_xor(tr, 32, 64));
      float dm = fmaxf(tr, 0.f);
      float alpha = fexp2(-dm);
      lsum *= alpha;
      acc[0] *= alpha; acc[1] *= alpha; acc[2] *= alpha; acc[3] *= alpha;
      m += dm;
      #pragma unroll
      for (int ks = 0; ks < 4; ++ks) {
        p[ks * 4 + 0] = fexp2(s[ks][0] - dm);
        p[ks * 4 + 1] = fexp2(s[ks][1] - dm);
        p[ks * 4 + 2] = fexp2(s[ks][2] - dm);
        p[ks * 4 + 3] = fexp2(s[ks][3] - dm);
      }
    } else {
      #pragma unroll
      for (int ks = 0; ks < 4; ++ks) {
        p[ks * 4 + 0] = fexp2(s[ks][0]);
        p[ks * 4 + 1] = fexp2(s[ks][1]);
        p[ks * 4 + 2] = fexp2(s[ks][2]);
        p[ks * 4 + 3] = fexp2(s[ks][3]);
      }
    }
    float q01 = p[0] + p[1],   q23 = p[2] + p[3];
    float q45 = p[4] + p[5],   q67 = p[6] + p[7];
    float q89 = p[8] + p[9],   qab = p[10] + p[11];
    float qcd = p[12] + p[13], qef = p[14] + p[15];
    lsum += ((q01 + q23) + (q45 + q67)) + ((q89 + qab) + (qcd + qef));

    union { u32 w4[4]; bf16x8 v; } pb0, pb1;
    pb0.w4[0] = cvtpk(p[0], p[1]);   pb0.w4[1] = cvtpk(p[2], p[3]);
    pb0.w4[2] = cvtpk(p[4], p[5]);   pb0.w4[3] = cvtpk(p[6], p[7]);
    pb1.w4[0] = cvtpk(p[8], p[9]);   pb1.w4[1] = cvtpk(p[10], p[11]);
    pb1.w4[2] = cvtpk(p[12], p[13]); pb1.w4[3] = cvtpk(p[14], p[15]);

    __builtin_amdgcn_s_setprio(1);
    #pragma unroll
    for (int dt = 0; dt < 4; ++dt) {
      int row = dt * 16 + q;
      int4 v0 = *(const int4*)&Vb[row * 64 + ((g ^ qs) * 8)];
      int4 v1 = *(const int4*)&Vb[row * 64 + (((4 + g) ^ qs) * 8)];
      acc[dt] = __builtin_amdgcn_mfma_f32_16x16x32_bf16(__builtin_bit_cast(bf16x8, v0), pb0.v, acc[dt], 0, 0, 0);
      acc[dt] = __builtin_amdgcn_mfma_f32_16x16x32_bf16(__builtin_bit_cast(bf16x8, v1), pb1.v, acc[dt], 0, 0, 0);
    }
    __builtin_amdgcn_s_setprio(0);

    if (kt < 14) {
      asm volatile("s_waitcnt vmcnt(4)" ::: "memory");
    } else {
      asm volatile("s_waitcnt vmcnt(0)" ::: "memory");
    }
    __builtin_amdgcn_s_barrier();
    __builtin_amdgcn_sched_barrier(0);
  }
  #undef STAGE

  lsum += __shfl_xor(lsum, 16, 64);
  lsum += __shfl_xor(lsum, 32, 64);
  float inv = 1.0f / lsum;

  float* oT = (float*)S + (size_t)w * 1088;
  #pragma unroll
  for (int dt = 0; dt < 4; ++dt) {
    oT[(dt * 16 + g * 4 + 0) * 17 + q] = acc[dt][0] * inv;
    oT[(dt * 16 + g * 4 + 1) * 17 + q] = acc[dt][1] * inv;
    oT[(dt * 16 + g * 4 + 2) * 17 + q] = acc[dt][2] * inv;
    oT[(dt * 16 + g * 4 + 3) * 17 + q] = acc[dt][3] * inv;
  }
  asm volatile("s_waitcnt lgkmcnt(0)" ::: "memory");
  int oq = lane >> 2, dc = (lane & 3) * 16;
  float* orow = out + (size_t)(b * F + q0 + oq) * 1024 + h * 64 + dc;
  #pragma unroll
  for (int c4 = 0; c4 < 4; ++c4) {
    float4 v;
    v.x = oT[(dc + c4 * 4 + 0) * 17 + oq];
    v.y = oT[(dc + c4 * 4 + 1) * 17 + oq];
    v.z = oT[(dc + c4 * 4 + 2) * 17 + oq];
    v.w = oT[(dc + c4 * 4 + 3) * 17 + oq];
    *(float4*)(orow + c4 * 4) = v;
  }
}

// ---------------------------------------------------------------------------
extern "C" void kernel_launch(void* const* d_in, const int* in_sizes, int n_in,
                              void* d_out, int out_size, void* d_ws, size_t ws_size,
                              hipStream_t stream) {
  const float* x     = (const float*)d_in[0];
  const float* gamma = (const float*)d_in[1];
  const float* beta  = (const float*)d_in[2];
  const float* W     = (const float*)d_in[3];
  const float* bias  = (const float*)d_in[4];
  float* out = (float*)d_out;

  char* ws = (char*)d_ws;
  u16* xn  = (u16*)ws;                                   // 16 MB
  u16* Wb  = (u16*)(ws + (size_t)16 * 1024 * 1024);      //  6 MB
  u16* qkv = (u16*)(ws + (size_t)22 * 1024 * 1024);      // 48 MB
  u16* Vt  = (u16*)(ws + (size_t)70 * 1024 * 1024);      // 16 MB

  bn_norm_kernel<<<1024, 256, 0, stream>>>(x, gamma, beta, xn);
  wconv_kernel<<<768, 256, 0, stream>>>(W, Wb);
  gemm_qkv_kernel<<<384, 512, 0, stream>>>(xn, Wb, bias, qkv);
  vt_kernel<<<dim3(16, 128), 256, 0, stream>>>(qkv, Vt);
  attn_kernel<<<2048, 256, 0, stream>>>(qkv, Vt, out);
}

// Round 15
// 163.213 us; speedup vs baseline: 1.0454x; 1.0054x over previous
//
#include <hip/hip_runtime.h>

typedef unsigned short u16;
typedef unsigned int   u32;

typedef __bf16 bf16x8 __attribute__((ext_vector_type(8)));
typedef float  f32x4  __attribute__((ext_vector_type(4)));

typedef const __attribute__((address_space(1))) void* gas_ptr;
typedef __attribute__((address_space(3))) void* las_ptr;

__device__ __forceinline__ u16 f2bf(float f) {
  u32 u = __builtin_bit_cast(u32, f);
  u += 0x7fffu + ((u >> 16) & 1u);
  return (u16)(u >> 16);
}
__device__ __forceinline__ float bf2f(u16 u) {
  return __builtin_bit_cast(float, ((u32)u) << 16);
}
// packed f32->bf16x2 hardware convert (RTNE), 1 VALU op per pair
__device__ __forceinline__ u32 cvtpk(float a, float b) {
  u32 r;
  asm("v_cvt_pk_bf16_f32 %0, %1, %2" : "=v"(r) : "v"(a), "v"(b));
  return r;
}
// raw v_exp_f32 (2^x, ~1ulp)
__device__ __forceinline__ float fexp2(float x) {
  return __builtin_amdgcn_exp2f(x);
}

// ---------------------------------------------------------------------------
// Kernel 1: BatchNorm over F-channels (stats over B,E) + bf16 cast.
// ---------------------------------------------------------------------------
__global__ __launch_bounds__(256) void bn_norm_kernel(
    const float* __restrict__ x, const float* __restrict__ gamma,
    const float* __restrict__ beta, u16* __restrict__ xn) {
  const int F = 1024, E = 1024;
  int f = blockIdx.x;
  __shared__ float sh[8192];
  __shared__ float ps[4], pq[4], sc[2];

  const float* xf = x + (size_t)f * E;
  float ls = 0.f, lq = 0.f;
  for (int i = threadIdx.x; i < 8192; i += 256) {
    int b = i >> 10, e = i & 1023;
    float v = xf[(size_t)b * F * E + e];
    sh[i] = v;
    ls += v;
    lq += v * v;
  }
  #pragma unroll
  for (int o = 32; o > 0; o >>= 1) {
    ls += __shfl_down(ls, o, 64);
    lq += __shfl_down(lq, o, 64);
  }
  int w = threadIdx.x >> 6;
  if ((threadIdx.x & 63) == 0) { ps[w] = ls; pq[w] = lq; }
  __syncthreads();
  if (threadIdx.x == 0) {
    float s = ps[0] + ps[1] + ps[2] + ps[3];
    float q = pq[0] + pq[1] + pq[2] + pq[3];
    float mean = s * (1.f / 8192.f);
    float var = q * (1.f / 8192.f) - mean * mean;
    float scale = gamma[f] * rsqrtf(var + 1e-5f);
    sc[0] = scale;
    sc[1] = beta[f] - mean * scale;
  }
  __syncthreads();
  float scale = sc[0], shift = sc[1];
  for (int i = threadIdx.x; i < 8192; i += 256) {
    int b = i >> 10, e = i & 1023;
    xn[((size_t)(b * F + f)) * E + e] = f2bf(sh[i] * scale + shift);
  }
}

// ---------------------------------------------------------------------------
// Kernel 2: W_qkv f32 -> bf16
// ---------------------------------------------------------------------------
__global__ __launch_bounds__(256) void wconv_kernel(
    const float* __restrict__ W, u16* __restrict__ Wb) {
  const int total = 3072 * 1024 / 4;
  for (int i = blockIdx.x * 256 + threadIdx.x; i < total; i += gridDim.x * 256) {
    float4 v = ((const float4*)W)[i];
    ushort4 o;
    o.x = f2bf(v.x); o.y = f2bf(v.y); o.z = f2bf(v.z); o.w = f2bf(v.w);
    ((ushort4*)Wb)[i] = o;
  }
}

// ---------------------------------------------------------------------------
// Kernel 3: GEMM (m97 structure + double-buffer, prefetch-early, 1 barrier/step)
//  C[m][n] = sum_k A[m][k]*Bw[n][k] + bias[n]
//  - identical tile geometry to the 68.8us m97 kernel (128x128, BK=32, 4 waves)
//  - STAGE(t+1) issued BEFORE compute(t); single __syncthreads per step:
//    the vmcnt(0) drain inside syncthreads now waits on ~600cy-old loads.
// ---------------------------------------------------------------------------
__global__ __launch_bounds__(256) void gemm_qkv_kernel(
    const u16* __restrict__ A, const u16* __restrict__ Bw,
    const float* __restrict__ bias, u16* __restrict__ C) {
  const int K = 1024, N = 3072;
  __shared__ u16 As[2][128 * 32];
  __shared__ u16 Bs[2][128 * 32];

  int m0 = blockIdx.x * 128, n0 = blockIdx.y * 128;
  int t = threadIdx.x, lane = t & 63, w = t >> 6;
  int wr = w >> 1, wc = w & 1;
  int r = lane & 15, g = lane >> 4;

  int srow = t >> 2, scol = (t & 3) * 8;
  const u16* gA  = A  + (size_t)(m0 + srow) * K + scol;
  const u16* gA2 = gA + (size_t)64 * K;
  const u16* gB  = Bw + (size_t)(n0 + srow) * K + scol;
  const u16* gB2 = gB + (size_t)64 * K;

  f32x4 acc[4][4] = {};

  #define GSTAGE(buf, k0)                                                      \
    do {                                                                       \
      __builtin_amdgcn_global_load_lds((gas_ptr)(gA + (k0)),                   \
          (las_ptr)&As[buf][t * 8], 16, 0, 0);                                 \
      __builtin_amdgcn_global_load_lds((gas_ptr)(gA2 + (k0)),                  \
          (las_ptr)&As[buf][2048 + t * 8], 16, 0, 0);                          \
      __builtin_amdgcn_global_load_lds((gas_ptr)(gB + (k0)),                   \
          (las_ptr)&Bs[buf][t * 8], 16, 0, 0);                                 \
      __builtin_amdgcn_global_load_lds((gas_ptr)(gB2 + (k0)),                  \
          (las_ptr)&Bs[buf][2048 + t * 8], 16, 0, 0);                          \
    } while (0)

  GSTAGE(0, 0);
  __syncthreads();

  for (int kt = 0; kt < 32; ++kt) {
    int cur = kt & 1;
    // prefetch next tile into the other buffer BEFORE compute (R4-attn pattern)
    if (kt < 31) GSTAGE(cur ^ 1, (kt + 1) * 32);

    const u16* pA = &As[cur][(wr * 64 + r) * 32 + g * 8];
    const u16* pB = &Bs[cur][(wc * 64 + r) * 32 + g * 8];

    bf16x8 af[4], bfr[4];
    #pragma unroll
    for (int mi = 0; mi < 4; ++mi)
      af[mi] = __builtin_bit_cast(bf16x8, *(const int4*)(pA + mi * 512));
    #pragma unroll
    for (int ni = 0; ni < 4; ++ni)
      bfr[ni] = __builtin_bit_cast(bf16x8, *(const int4*)(pB + ni * 512));
    #pragma unroll
    for (int mi = 0; mi < 4; ++mi)
      #pragma unroll
      for (int ni = 0; ni < 4; ++ni)
        acc[mi][ni] = __builtin_amdgcn_mfma_f32_16x16x32_bf16(af[mi], bfr[ni], acc[mi][ni], 0, 0, 0);

    // single barrier per step: drains this wave's stage loads (issued ~600cy
    // ago) and publishes buf cur^1 for the next iteration.
    __syncthreads();
  }
  #undef GSTAGE

  #pragma unroll
  for (int ni = 0; ni < 4; ++ni) {
    int col = n0 + wc * 64 + ni * 16 + r;
    float bv = bias[col];
    #pragma unroll
    for (int mi = 0; mi < 4; ++mi) {
      int row = m0 + wr * 64 + mi * 16 + g * 4;
      #pragma unroll
      for (int j = 0; j < 4; ++j)
        C[(size_t)(row + j) * N + col] = f2bf(acc[mi][ni][j] + bv);
    }
  }
}

// ---------------------------------------------------------------------------
// Kernel 3b: V transpose WITH baked key permutation (verified R3).
// ---------------------------------------------------------------------------
__global__ __launch_bounds__(256) void vt_kernel(
    const u16* __restrict__ qkv, u16* __restrict__ Vt) {
  __shared__ u16 T[64][72];
  int bh = blockIdx.y, b = bh >> 4, h = bh & 15;
  int f0 = blockIdx.x * 64;
  int t = threadIdx.x;
  int fl = t >> 2, c16 = (t & 3) * 16;
  const u16* src = qkv + (size_t)(b * 1024 + f0 + fl) * 3072 + h * 192 + 128 + c16;
  *(int4*)&T[fl][c16]     = *(const int4*)src;
  *(int4*)&T[fl][c16 + 8] = *(const int4*)(src + 8);
  __syncthreads();
  int dl = t >> 2, fc = (t & 3) * 16;
  u16 buf[16];
  #pragma unroll
  for (int j = 0; j < 16; ++j) {
    int c = fc + j;
    int m = c & 31;
    int a = ((m & 4) << 2) | ((m & 16) >> 1) | ((m & 8) >> 1) | (m & 3);
    buf[j] = T[(c & 32) | a][dl];
  }
  u16* dst = Vt + (size_t)bh * 65536 + (size_t)dl * 1024 + f0 + fc;
  *(int4*)dst       = *(int4*)&buf[0];
  *(int4*)(dst + 8) = *(int4*)&buf[8];
}

// ---------------------------------------------------------------------------
// Kernel 4: flash attention v9 (R12 winner, 69.6us) — raw v_exp, full unroll,
// triple-buffered K/V, counted-vmcnt pipeline, seeded-C softmax.
// ---------------------------------------------------------------------------
__global__ __launch_bounds__(256) void attn_kernel(
    const u16* __restrict__ qkv, const u16* __restrict__ Vt,
    float* __restrict__ out) {
  const int F = 1024, NQ = 3072;
  int bid = blockIdx.x;           // 2048 blocks
  int xcd = bid & 7;
  int li  = bid >> 3;             // 0..255
  int bh  = ((li >> 4) << 3) | xcd;
  int ql  = li & 15;
  int w   = threadIdx.x >> 6;
  int lane = threadIdx.x & 63;
  int q = lane & 15, g = lane >> 4;
  int qs = q & 7;
  int q0 = ql * 64 + w * 16;
  int b = bh >> 4, h = bh & 15;

  const u16* base = qkv + (size_t)b * F * NQ + h * 192;
  const u16* VtBH = Vt + (size_t)bh * 65536;

  __shared__ u16 S[24576];

  int i8 = lane >> 3;
  int ic = lane & 7;

  const float qscale = 0.125f * 1.4426950408889634f;
  bf16x8 Qf0, Qf1;
  {
    const u16* qp = base + (size_t)(q0 + q) * NQ + g * 8;
    union { int4 v; u16 u[8]; } uu0, uu1;
    uu0.v = *(const int4*)(qp);
    uu1.v = *(const int4*)(qp + 32);
    union { u32 w4[4]; bf16x8 v; } p0, p1;
    #pragma unroll
    for (int j = 0; j < 4; ++j) {
      p0.w4[j] = cvtpk(bf2f(uu0.u[2 * j]) * qscale, bf2f(uu0.u[2 * j + 1]) * qscale);
      p1.w4[j] = cvtpk(bf2f(uu1.u[2 * j]) * qscale, bf2f(uu1.u[2 * j + 1]) * qscale);
    }
    Qf0 = p0.v; Qf1 = p1.v;
  }

  f32x4 acc[4] = {};
  float m = 0.0f, lsum = 0.f;

  #define STAGE(buf, kt)                                                       \
    do {                                                                       \
      int kb_ = (kt) * 64;                                                     \
      _Pragma("unroll")                                                        \
      for (int rr = 0; rr < 2; ++rr) {                                         \
        int r_ = rr * 32 + w * 8 + i8;                                         \
        int sc_ = (ic ^ (r_ & 7)) * 8;                                         \
        const u16* ks_ = base + (size_t)(kb_ + r_) * NQ + 64 + sc_;            \
        const u16* vs_ = VtBH + (size_t)r_ * 1024 + kb_ + sc_;                 \
        __builtin_amdgcn_global_load_lds((gas_ptr)ks_,                         \
            (las_ptr)&S[(buf) * 4096 + (rr * 32 + w * 8) * 64], 16, 0, 0);     \
        __builtin_amdgcn_global_load_lds((gas_ptr)vs_,                         \
            (las_ptr)&S[12288 + (buf) * 4096 + (rr * 32 + w * 8) * 64], 16, 0, 0);\
      }                                                                        \
    } while (0)

  __builtin_amdgcn_sched_barrier(0);
  STAGE(0, 0);
  STAGE(1, 1);
  asm volatile("s_waitcnt vmcnt(4)" ::: "memory");
  __builtin_amdgcn_s_barrier();
  __builtin_amdgcn_sched_barrier(0);

  #pragma unroll
  for (int kt = 0; kt < 16; ++kt) {
    const int cur = kt % 3;
    const int stg = (kt + 2) % 3;
    if (kt < 14) STAGE(stg, kt + 2);

    const u16* Kb = &S[cur * 4096];
    const u16* Vb = &S[12288 + cur * 4096];

    f32x4 s[4];
    f32x4 seed = {-m, -m, -m, -m};
    __builtin_amdgcn_s_setprio(1);
    #pragma unroll
    for (int ks = 0; ks < 4; ++ks) {
      int row = ks * 16 + q;
      int4 k0 = *(const int4*)&Kb[row * 64 + ((g ^ qs) * 8)];
      int4 k1 = *(const int4*)&Kb[row * 64 + (((4 + g) ^ qs) * 8)];
      f32x4 sv = seed;
      sv = __builtin_amdgcn_mfma_f32_16x16x32_bf16(__builtin_bit_cast(bf16x8, k0), Qf0, sv, 0, 0, 0);
      sv = __builtin_amdgcn_mfma_f32_16x16x32_bf16(__builtin_bit_cast(bf16x8, k1), Qf1, sv, 0, 0, 0);
      s[ks] = sv;
    }
    __builtin_amdgcn_s_setprio(0);

    float a0 = fmaxf(fmaxf(s[0][0], s[0][1]), s[0][2]);
    float a1 = fmaxf(fmaxf(s[0][3], s[1][0]), s[1][1]);
    float a2 = fmaxf(fmaxf(s[1][2], s[1][3]), s[2][0]);
    float a3 = fmaxf(fmaxf(s[2][1], s[2][2]), s[2][3]);
    float a4 = fmaxf(fmaxf(s[3][0], s[3][1]), s[3][2]);
    float tmx = fmaxf(fmaxf(fmaxf(a0, a1), a2), fmaxf(fmaxf(a3, a4), s[3][3]));

    float p[16];
    if (__builtin_expect(__any(tmx > 8.0f), 0)) {
      float tr = fmaxf(tmx, __shfl_xor(tmx, 16, 64));
      tr = fmaxf(tr, __shfl_xor(tr, 32, 64));
      float dm = fmaxf(tr, 0.f);
      float alpha = fexp2(-dm);
      lsum *= alpha;
      acc[0] *= alpha; acc[1] *= alpha; acc[2] *= alpha; acc[3] *= alpha;
      m += dm;
      #pragma unroll
      for (int ks = 0; ks < 4; ++ks) {
        p[ks * 4 + 0] = fexp2(s[ks][0] - dm);
        p[ks * 4 + 1] = fexp2(s[ks][1] - dm);
        p[ks * 4 + 2] = fexp2(s[ks][2] - dm);
        p[ks * 4 + 3] = fexp2(s[ks][3] - dm);
      }
    } else {
      #pragma unroll
      for (int ks = 0; ks < 4; ++ks) {
        p[ks * 4 + 0] = fexp2(s[ks][0]);
        p[ks * 4 + 1] = fexp2(s[ks][1]);
        p[ks * 4 + 2] = fexp2(s[ks][2]);
        p[ks * 4 + 3] = fexp2(s[ks][3]);
      }
    }
    float q01 = p[0] + p[1],   q23 = p[2] + p[3];
    float q45 = p[4] + p[5],   q67 = p[6] + p[7];
    float q89 = p[8] + p[9],   qab = p[10] + p[11];
    float qcd = p[12] + p[13], qef = p[14] + p[15];
    lsum += ((q01 + q23) + (q45 + q67)) + ((q89 + qab) + (qcd + qef));

    union { u32 w4[4]; bf16x8 v; } pb0, pb1;
    pb0.w4[0] = cvtpk(p[0], p[1]);   pb0.w4[1] = cvtpk(p[2], p[3]);
    pb0.w4[2] = cvtpk(p[4], p[5]);   pb0.w4[3] = cvtpk(p[6], p[7]);
    pb1.w4[0] = cvtpk(p[8], p[9]);   pb1.w4[1] = cvtpk(p[10], p[11]);
    pb1.w4[2] = cvtpk(p[12], p[13]); pb1.w4[3] = cvtpk(p[14], p[15]);

    __builtin_amdgcn_s_setprio(1);
    #pragma unroll
    for (int dt = 0; dt < 4; ++dt) {
      int row = dt * 16 + q;
      int4 v0 = *(const int4*)&Vb[row * 64 + ((g ^ qs) * 8)];
      int4 v1 = *(const int4*)&Vb[row * 64 + (((4 + g) ^ qs) * 8)];
      acc[dt] = __builtin_amdgcn_mfma_f32_16x16x32_bf16(__builtin_bit_cast(bf16x8, v0), pb0.v, acc[dt], 0, 0, 0);
      acc[dt] = __builtin_amdgcn_mfma_f32_16x16x32_bf16(__builtin_bit_cast(bf16x8, v1), pb1.v, acc[dt], 0, 0, 0);
    }
    __builtin_amdgcn_s_setprio(0);

    if (kt < 14) {
      asm volatile("s_waitcnt vmcnt(4)" ::: "memory");
    } else {
      asm volatile("s_waitcnt vmcnt(0)" ::: "memory");
    }
    __builtin_amdgcn_s_barrier();
    __builtin_amdgcn_sched_barrier(0);
  }
  #undef STAGE

  lsum += __shfl_xor(lsum, 16, 64);
  lsum += __shfl_xor(lsum, 32, 64);
  float inv = 1.0f / lsum;

  float* oT = (float*)S + (size_t)w * 1088;
  #pragma unroll
  for (int dt = 0; dt < 4; ++dt) {
    oT[(dt * 16 + g * 4 + 0) * 17 + q] = acc[dt][0] * inv;
    oT[(dt * 16 + g * 4 + 1) * 17 + q] = acc[dt][1] * inv;
    oT[(dt * 16 + g * 4 + 2) * 17 + q] = acc[dt][2] * inv;
    oT[(dt * 16 + g * 4 + 3) * 17 + q] = acc[dt][3] * inv;
  }
  asm volatile("s_waitcnt lgkmcnt(0)" ::: "memory");
  int oq = lane >> 2, dc = (lane & 3) * 16;
  float* orow = out + (size_t)(b * F + q0 + oq) * 1024 + h * 64 + dc;
  #pragma unroll
  for (int c4 = 0; c4 < 4; ++c4) {
    float4 v;
    v.x = oT[(dc + c4 * 4 + 0) * 17 + oq];
    v.y = oT[(dc + c4 * 4 + 1) * 17 + oq];
    v.z = oT[(dc + c4 * 4 + 2) * 17 + oq];
    v.w = oT[(dc + c4 * 4 + 3) * 17 + oq];
    *(float4*)(orow + c4 * 4) = v;
  }
}

// ---------------------------------------------------------------------------
extern "C" void kernel_launch(void* const* d_in, const int* in_sizes, int n_in,
                              void* d_out, int out_size, void* d_ws, size_t ws_size,
                              hipStream_t stream) {
  const float* x     = (const float*)d_in[0];
  const float* gamma = (const float*)d_in[1];
  const float* beta  = (const float*)d_in[2];
  const float* W     = (const float*)d_in[3];
  const float* bias  = (const float*)d_in[4];
  float* out = (float*)d_out;

  char* ws = (char*)d_ws;
  u16* xn  = (u16*)ws;                                   // 16 MB
  u16* Wb  = (u16*)(ws + (size_t)16 * 1024 * 1024);      //  6 MB
  u16* qkv = (u16*)(ws + (size_t)22 * 1024 * 1024);      // 48 MB
  u16* Vt  = (u16*)(ws + (size_t)70 * 1024 * 1024);      // 16 MB

  bn_norm_kernel<<<1024, 256, 0, stream>>>(x, gamma, beta, xn);
  wconv_kernel<<<768, 256, 0, stream>>>(W, Wb);
  gemm_qkv_kernel<<<dim3(64, 24), 256, 0, stream>>>(xn, Wb, bias, qkv);
  vt_kernel<<<dim3(16, 128), 256, 0, stream>>>(qkv, Vt);
  attn_kernel<<<2048, 256, 0, stream>>>(qkv, Vt, out);
}

// Round 16
// 151.838 us; speedup vs baseline: 1.1238x; 1.0749x over previous
//
#include <hip/hip_runtime.h>

typedef unsigned short u16;
typedef unsigned int   u32;

typedef __bf16 bf16x8 __attribute__((ext_vector_type(8)));
typedef float  f32x4  __attribute__((ext_vector_type(4)));

typedef const __attribute__((address_space(1))) void* gas_ptr;
typedef __attribute__((address_space(3))) void* las_ptr;

__device__ __forceinline__ u16 f2bf(float f) {
  u32 u = __builtin_bit_cast(u32, f);
  u += 0x7fffu + ((u >> 16) & 1u);
  return (u16)(u >> 16);
}
__device__ __forceinline__ float bf2f(u16 u) {
  return __builtin_bit_cast(float, ((u32)u) << 16);
}
// packed f32->bf16x2 hardware convert (RTNE), 1 VALU op per pair
__device__ __forceinline__ u32 cvtpk(float a, float b) {
  u32 r;
  asm("v_cvt_pk_bf16_f32 %0, %1, %2" : "=v"(r) : "v"(a), "v"(b));
  return r;
}
// raw v_exp_f32 (2^x, ~1ulp)
__device__ __forceinline__ float fexp2(float x) {
  return __builtin_amdgcn_exp2f(x);
}

// ---------------------------------------------------------------------------
// Kernel 1: BatchNorm over F-channels (stats over B,E) + bf16 cast.
// ---------------------------------------------------------------------------
__global__ __launch_bounds__(256) void bn_norm_kernel(
    const float* __restrict__ x, const float* __restrict__ gamma,
    const float* __restrict__ beta, u16* __restrict__ xn) {
  const int F = 1024, E = 1024;
  int f = blockIdx.x;
  __shared__ float sh[8192];
  __shared__ float ps[4], pq[4], sc[2];

  const float* xf = x + (size_t)f * E;
  float ls = 0.f, lq = 0.f;
  for (int i = threadIdx.x; i < 8192; i += 256) {
    int b = i >> 10, e = i & 1023;
    float v = xf[(size_t)b * F * E + e];
    sh[i] = v;
    ls += v;
    lq += v * v;
  }
  #pragma unroll
  for (int o = 32; o > 0; o >>= 1) {
    ls += __shfl_down(ls, o, 64);
    lq += __shfl_down(lq, o, 64);
  }
  int w = threadIdx.x >> 6;
  if ((threadIdx.x & 63) == 0) { ps[w] = ls; pq[w] = lq; }
  __syncthreads();
  if (threadIdx.x == 0) {
    float s = ps[0] + ps[1] + ps[2] + ps[3];
    float q = pq[0] + pq[1] + pq[2] + pq[3];
    float mean = s * (1.f / 8192.f);
    float var = q * (1.f / 8192.f) - mean * mean;
    float scale = gamma[f] * rsqrtf(var + 1e-5f);
    sc[0] = scale;
    sc[1] = beta[f] - mean * scale;
  }
  __syncthreads();
  float scale = sc[0], shift = sc[1];
  for (int i = threadIdx.x; i < 8192; i += 256) {
    int b = i >> 10, e = i & 1023;
    xn[((size_t)(b * F + f)) * E + e] = f2bf(sh[i] * scale + shift);
  }
}

// ---------------------------------------------------------------------------
// Kernel 2: W_qkv f32 -> bf16
// ---------------------------------------------------------------------------
__global__ __launch_bounds__(256) void wconv_kernel(
    const float* __restrict__ W, u16* __restrict__ Wb) {
  const int total = 3072 * 1024 / 4;
  for (int i = blockIdx.x * 256 + threadIdx.x; i < total; i += gridDim.x * 256) {
    float4 v = ((const float4*)W)[i];
    ushort4 o;
    o.x = f2bf(v.x); o.y = f2bf(v.y); o.z = f2bf(v.z); o.w = f2bf(v.w);
    ((ushort4*)Wb)[i] = o;
  }
}

// ---------------------------------------------------------------------------
// Kernel 3: GEMM (m97 structure, 68.8us base) + bank-conflict swizzle ONLY.
//  C[m][n] = sum_k A[m][k]*Bw[n][k] + bias[n]
//  Swizzle (R13-verified, conflicts 6.29M -> 0): chunk ^= (row>>1)&3,
//  applied source-side at staging (linear LDS dest) and on fragment reads.
//  XOR term is mi/ni-invariant: row steps of 16 vanish mod 4 after >>1.
// ---------------------------------------------------------------------------
__global__ __launch_bounds__(256) void gemm_qkv_kernel(
    const u16* __restrict__ A, const u16* __restrict__ Bw,
    const float* __restrict__ bias, u16* __restrict__ C) {
  const int K = 1024, N = 3072;
  __shared__ u16 As[128 * 32];
  __shared__ u16 Bs[128 * 32];

  int m0 = blockIdx.x * 128, n0 = blockIdx.y * 128;
  int t = threadIdx.x, lane = t & 63, w = t >> 6;
  int wr = w >> 1, wc = w & 1;
  int r = lane & 15, g = lane >> 4;

  int srow = t >> 2;
  int scol = ((t & 3) ^ ((srow >> 1) & 3)) * 8;   // pre-swizzled source chunk
  const u16* gA  = A  + (size_t)(m0 + srow) * K + scol;
  const u16* gA2 = A  + (size_t)(m0 + 64 + srow) * K + scol;
  const u16* gB  = Bw + (size_t)(n0 + srow) * K + scol;
  const u16* gB2 = Bw + (size_t)(n0 + 64 + srow) * K + scol;
  u16* lA  = As + t * 8;
  u16* lA2 = As + 2048 + t * 8;
  u16* lB  = Bs + t * 8;
  u16* lB2 = Bs + 2048 + t * 8;

  f32x4 acc[4][4] = {};

  // fragment read: actual chunk g lives at position g ^ ((r>>1)&3)
  int rc = (g ^ ((r >> 1) & 3)) * 8;
  const u16* pA = As + (size_t)(wr * 64 + r) * 32 + rc;
  const u16* pB = Bs + (size_t)(wc * 64 + r) * 32 + rc;

  for (int k0 = 0; k0 < K; k0 += 32) {
    __builtin_amdgcn_global_load_lds((gas_ptr)gA,  (las_ptr)lA,  16, 0, 0);
    __builtin_amdgcn_global_load_lds((gas_ptr)gA2, (las_ptr)lA2, 16, 0, 0);
    __builtin_amdgcn_global_load_lds((gas_ptr)gB,  (las_ptr)lB,  16, 0, 0);
    __builtin_amdgcn_global_load_lds((gas_ptr)gB2, (las_ptr)lB2, 16, 0, 0);
    gA += 32; gA2 += 32; gB += 32; gB2 += 32;
    __syncthreads();

    bf16x8 af[4], bfr[4];
    #pragma unroll
    for (int mi = 0; mi < 4; ++mi)
      af[mi] = __builtin_bit_cast(bf16x8, *(const int4*)(pA + mi * 512));
    #pragma unroll
    for (int ni = 0; ni < 4; ++ni)
      bfr[ni] = __builtin_bit_cast(bf16x8, *(const int4*)(pB + ni * 512));
    #pragma unroll
    for (int mi = 0; mi < 4; ++mi)
      #pragma unroll
      for (int ni = 0; ni < 4; ++ni)
        acc[mi][ni] = __builtin_amdgcn_mfma_f32_16x16x32_bf16(af[mi], bfr[ni], acc[mi][ni], 0, 0, 0);
    __syncthreads();
  }

  #pragma unroll
  for (int ni = 0; ni < 4; ++ni) {
    int col = n0 + wc * 64 + ni * 16 + r;
    float bv = bias[col];
    #pragma unroll
    for (int mi = 0; mi < 4; ++mi) {
      int row = m0 + wr * 64 + mi * 16 + g * 4;
      #pragma unroll
      for (int j = 0; j < 4; ++j)
        C[(size_t)(row + j) * N + col] = f2bf(acc[mi][ni][j] + bv);
    }
  }
}

// ---------------------------------------------------------------------------
// Kernel 3b: V transpose WITH baked key permutation (verified R3).
// ---------------------------------------------------------------------------
__global__ __launch_bounds__(256) void vt_kernel(
    const u16* __restrict__ qkv, u16* __restrict__ Vt) {
  __shared__ u16 T[64][72];
  int bh = blockIdx.y, b = bh >> 4, h = bh & 15;
  int f0 = blockIdx.x * 64;
  int t = threadIdx.x;
  int fl = t >> 2, c16 = (t & 3) * 16;
  const u16* src = qkv + (size_t)(b * 1024 + f0 + fl) * 3072 + h * 192 + 128 + c16;
  *(int4*)&T[fl][c16]     = *(const int4*)src;
  *(int4*)&T[fl][c16 + 8] = *(const int4*)(src + 8);
  __syncthreads();
  int dl = t >> 2, fc = (t & 3) * 16;
  u16 buf[16];
  #pragma unroll
  for (int j = 0; j < 16; ++j) {
    int c = fc + j;
    int m = c & 31;
    int a = ((m & 4) << 2) | ((m & 16) >> 1) | ((m & 8) >> 1) | (m & 3);
    buf[j] = T[(c & 32) | a][dl];
  }
  u16* dst = Vt + (size_t)bh * 65536 + (size_t)dl * 1024 + f0 + fc;
  *(int4*)dst       = *(int4*)&buf[0];
  *(int4*)(dst + 8) = *(int4*)&buf[8];
}

// ---------------------------------------------------------------------------
// Kernel 4: flash attention v9 (R12 winner, 69.6us) — raw v_exp, full unroll,
// triple-buffered K/V, counted-vmcnt pipeline, seeded-C softmax.
// ---------------------------------------------------------------------------
__global__ __launch_bounds__(256) void attn_kernel(
    const u16* __restrict__ qkv, const u16* __restrict__ Vt,
    float* __restrict__ out) {
  const int F = 1024, NQ = 3072;
  int bid = blockIdx.x;           // 2048 blocks
  int xcd = bid & 7;
  int li  = bid >> 3;             // 0..255
  int bh  = ((li >> 4) << 3) | xcd;
  int ql  = li & 15;
  int w   = threadIdx.x >> 6;
  int lane = threadIdx.x & 63;
  int q = lane & 15, g = lane >> 4;
  int qs = q & 7;
  int q0 = ql * 64 + w * 16;
  int b = bh >> 4, h = bh & 15;

  const u16* base = qkv + (size_t)b * F * NQ + h * 192;
  const u16* VtBH = Vt + (size_t)bh * 65536;

  __shared__ u16 S[24576];

  int i8 = lane >> 3;
  int ic = lane & 7;

  const float qscale = 0.125f * 1.4426950408889634f;
  bf16x8 Qf0, Qf1;
  {
    const u16* qp = base + (size_t)(q0 + q) * NQ + g * 8;
    union { int4 v; u16 u[8]; } uu0, uu1;
    uu0.v = *(const int4*)(qp);
    uu1.v = *(const int4*)(qp + 32);
    union { u32 w4[4]; bf16x8 v; } p0, p1;
    #pragma unroll
    for (int j = 0; j < 4; ++j) {
      p0.w4[j] = cvtpk(bf2f(uu0.u[2 * j]) * qscale, bf2f(uu0.u[2 * j + 1]) * qscale);
      p1.w4[j] = cvtpk(bf2f(uu1.u[2 * j]) * qscale, bf2f(uu1.u[2 * j + 1]) * qscale);
    }
    Qf0 = p0.v; Qf1 = p1.v;
  }

  f32x4 acc[4] = {};
  float m = 0.0f, lsum = 0.f;

  #define STAGE(buf, kt)                                                       \
    do {                                                                       \
      int kb_ = (kt) * 64;                                                     \
      _Pragma("unroll")                                                        \
      for (int rr = 0; rr < 2; ++rr) {                                         \
        int r_ = rr * 32 + w * 8 + i8;                                         \
        int sc_ = (ic ^ (r_ & 7)) * 8;                                         \
        const u16* ks_ = base + (size_t)(kb_ + r_) * NQ + 64 + sc_;            \
        const u16* vs_ = VtBH + (size_t)r_ * 1024 + kb_ + sc_;                 \
        __builtin_amdgcn_global_load_lds((gas_ptr)ks_,                         \
            (las_ptr)&S[(buf) * 4096 + (rr * 32 + w * 8) * 64], 16, 0, 0);     \
        __builtin_amdgcn_global_load_lds((gas_ptr)vs_,                         \
            (las_ptr)&S[12288 + (buf) * 4096 + (rr * 32 + w * 8) * 64], 16, 0, 0);\
      }                                                                        \
    } while (0)

  __builtin_amdgcn_sched_barrier(0);
  STAGE(0, 0);
  STAGE(1, 1);
  asm volatile("s_waitcnt vmcnt(4)" ::: "memory");
  __builtin_amdgcn_s_barrier();
  __builtin_amdgcn_sched_barrier(0);

  #pragma unroll
  for (int kt = 0; kt < 16; ++kt) {
    const int cur = kt % 3;
    const int stg = (kt + 2) % 3;
    if (kt < 14) STAGE(stg, kt + 2);

    const u16* Kb = &S[cur * 4096];
    const u16* Vb = &S[12288 + cur * 4096];

    f32x4 s[4];
    f32x4 seed = {-m, -m, -m, -m};
    __builtin_amdgcn_s_setprio(1);
    #pragma unroll
    for (int ks = 0; ks < 4; ++ks) {
      int row = ks * 16 + q;
      int4 k0 = *(const int4*)&Kb[row * 64 + ((g ^ qs) * 8)];
      int4 k1 = *(const int4*)&Kb[row * 64 + (((4 + g) ^ qs) * 8)];
      f32x4 sv = seed;
      sv = __builtin_amdgcn_mfma_f32_16x16x32_bf16(__builtin_bit_cast(bf16x8, k0), Qf0, sv, 0, 0, 0);
      sv = __builtin_amdgcn_mfma_f32_16x16x32_bf16(__builtin_bit_cast(bf16x8, k1), Qf1, sv, 0, 0, 0);
      s[ks] = sv;
    }
    __builtin_amdgcn_s_setprio(0);

    float a0 = fmaxf(fmaxf(s[0][0], s[0][1]), s[0][2]);
    float a1 = fmaxf(fmaxf(s[0][3], s[1][0]), s[1][1]);
    float a2 = fmaxf(fmaxf(s[1][2], s[1][3]), s[2][0]);
    float a3 = fmaxf(fmaxf(s[2][1], s[2][2]), s[2][3]);
    float a4 = fmaxf(fmaxf(s[3][0], s[3][1]), s[3][2]);
    float tmx = fmaxf(fmaxf(fmaxf(a0, a1), a2), fmaxf(fmaxf(a3, a4), s[3][3]));

    float p[16];
    if (__builtin_expect(__any(tmx > 8.0f), 0)) {
      float tr = fmaxf(tmx, __shfl_xor(tmx, 16, 64));
      tr = fmaxf(tr, __shfl_xor(tr, 32, 64));
      float dm = fmaxf(tr, 0.f);
      float alpha = fexp2(-dm);
      lsum *= alpha;
      acc[0] *= alpha; acc[1] *= alpha; acc[2] *= alpha; acc[3] *= alpha;
      m += dm;
      #pragma unroll
      for (int ks = 0; ks < 4; ++ks) {
        p[ks * 4 + 0] = fexp2(s[ks][0] - dm);
        p[ks * 4 + 1] = fexp2(s[ks][1] - dm);
        p[ks * 4 + 2] = fexp2(s[ks][2] - dm);
        p[ks * 4 + 3] = fexp2(s[ks][3] - dm);
      }
    } else {
      #pragma unroll
      for (int ks = 0; ks < 4; ++ks) {
        p[ks * 4 + 0] = fexp2(s[ks][0]);
        p[ks * 4 + 1] = fexp2(s[ks][1]);
        p[ks * 4 + 2] = fexp2(s[ks][2]);
        p[ks * 4 + 3] = fexp2(s[ks][3]);
      }
    }
    float q01 = p[0] + p[1],   q23 = p[2] + p[3];
    float q45 = p[4] + p[5],   q67 = p[6] + p[7];
    float q89 = p[8] + p[9],   qab = p[10] + p[11];
    float qcd = p[12] + p[13], qef = p[14] + p[15];
    lsum += ((q01 + q23) + (q45 + q67)) + ((q89 + qab) + (qcd + qef));

    union { u32 w4[4]; bf16x8 v; } pb0, pb1;
    pb0.w4[0] = cvtpk(p[0], p[1]);   pb0.w4[1] = cvtpk(p[2], p[3]);
    pb0.w4[2] = cvtpk(p[4], p[5]);   pb0.w4[3] = cvtpk(p[6], p[7]);
    pb1.w4[0] = cvtpk(p[8], p[9]);   pb1.w4[1] = cvtpk(p[10], p[11]);
    pb1.w4[2] = cvtpk(p[12], p[13]); pb1.w4[3] = cvtpk(p[14], p[15]);

    __builtin_amdgcn_s_setprio(1);
    #pragma unroll
    for (int dt = 0; dt < 4; ++dt) {
      int row = dt * 16 + q;
      int4 v0 = *(const int4*)&Vb[row * 64 + ((g ^ qs) * 8)];
      int4 v1 = *(const int4*)&Vb[row * 64 + (((4 + g) ^ qs) * 8)];
      acc[dt] = __builtin_amdgcn_mfma_f32_16x16x32_bf16(__builtin_bit_cast(bf16x8, v0), pb0.v, acc[dt], 0, 0, 0);
      acc[dt] = __builtin_amdgcn_mfma_f32_16x16x32_bf16(__builtin_bit_cast(bf16x8, v1), pb1.v, acc[dt], 0, 0, 0);
    }
    __builtin_amdgcn_s_setprio(0);

    if (kt < 14) {
      asm volatile("s_waitcnt vmcnt(4)" ::: "memory");
    } else {
      asm volatile("s_waitcnt vmcnt(0)" ::: "memory");
    }
    __builtin_amdgcn_s_barrier();
    __builtin_amdgcn_sched_barrier(0);
  }
  #undef STAGE

  lsum += __shfl_xor(lsum, 16, 64);
  lsum += __shfl_xor(lsum, 32, 64);
  float inv = 1.0f / lsum;

  float* oT = (float*)S + (size_t)w * 1088;
  #pragma unroll
  for (int dt = 0; dt < 4; ++dt) {
    oT[(dt * 16 + g * 4 + 0) * 17 + q] = acc[dt][0] * inv;
    oT[(dt * 16 + g * 4 + 1) * 17 + q] = acc[dt][1] * inv;
    oT[(dt * 16 + g * 4 + 2) * 17 + q] = acc[dt][2] * inv;
    oT[(dt * 16 + g * 4 + 3) * 17 + q] = acc[dt][3] * inv;
  }
  asm volatile("s_waitcnt lgkmcnt(0)" ::: "memory");
  int oq = lane >> 2, dc = (lane & 3) * 16;
  float* orow = out + (size_t)(b * F + q0 + oq) * 1024 + h * 64 + dc;
  #pragma unroll
  for (int c4 = 0; c4 < 4; ++c4) {
    float4 v;
    v.x = oT[(dc + c4 * 4 + 0) * 17 + oq];
    v.y = oT[(dc + c4 * 4 + 1) * 17 + oq];
    v.z = oT[(dc + c4 * 4 + 2) * 17 + oq];
    v.w = oT[(dc + c4 * 4 + 3) * 17 + oq];
    *(float4*)(orow + c4 * 4) = v;
  }
}

// ---------------------------------------------------------------------------
extern "C" void kernel_launch(void* const* d_in, const int* in_sizes, int n_in,
                              void* d_out, int out_size, void* d_ws, size_t ws_size,
                              hipStream_t stream) {
  const float* x     = (const float*)d_in[0];
  const float* gamma = (const float*)d_in[1];
  const float* beta  = (const float*)d_in[2];
  const float* W     = (const float*)d_in[3];
  const float* bias  = (const float*)d_in[4];
  float* out = (float*)d_out;

  char* ws = (char*)d_ws;
  u16* xn  = (u16*)ws;                                   // 16 MB
  u16* Wb  = (u16*)(ws + (size_t)16 * 1024 * 1024);      //  6 MB
  u16* qkv = (u16*)(ws + (size_t)22 * 1024 * 1024);      // 48 MB
  u16* Vt  = (u16*)(ws + (size_t)70 * 1024 * 1024);      // 16 MB

  bn_norm_kernel<<<1024, 256, 0, stream>>>(x, gamma, beta, xn);
  wconv_kernel<<<768, 256, 0, stream>>>(W, Wb);
  gemm_qkv_kernel<<<dim3(64, 24), 256, 0, stream>>>(xn, Wb, bias, qkv);
  vt_kernel<<<dim3(16, 128), 256, 0, stream>>>(qkv, Vt);
  attn_kernel<<<2048, 256, 0, stream>>>(qkv, Vt, out);
}

// Round 17
// 144.393 us; speedup vs baseline: 1.1817x; 1.0516x over previous
//
#include <hip/hip_runtime.h>

typedef unsigned short u16;
typedef unsigned int   u32;

typedef __bf16 bf16x8 __attribute__((ext_vector_type(8)));
typedef float  f32x4  __attribute__((ext_vector_type(4)));

typedef const __attribute__((address_space(1))) void* gas_ptr;
typedef __attribute__((address_space(3))) void* las_ptr;

__device__ __forceinline__ u16 f2bf(float f) {
  u32 u = __builtin_bit_cast(u32, f);
  u += 0x7fffu + ((u >> 16) & 1u);
  return (u16)(u >> 16);
}
__device__ __forceinline__ float bf2f(u16 u) {
  return __builtin_bit_cast(float, ((u32)u) << 16);
}
// packed f32->bf16x2 hardware convert (RTNE), 1 VALU op per pair
__device__ __forceinline__ u32 cvtpk(float a, float b) {
  u32 r;
  asm("v_cvt_pk_bf16_f32 %0, %1, %2" : "=v"(r) : "v"(a), "v"(b));
  return r;
}
// raw v_exp_f32 (2^x, ~1ulp)
__device__ __forceinline__ float fexp2(float x) {
  return __builtin_amdgcn_exp2f(x);
}

// ---------------------------------------------------------------------------
// Kernel 1: BatchNorm over F-channels (stats over B,E) + bf16 cast.
// ---------------------------------------------------------------------------
__global__ __launch_bounds__(256) void bn_norm_kernel(
    const float* __restrict__ x, const float* __restrict__ gamma,
    const float* __restrict__ beta, u16* __restrict__ xn) {
  const int F = 1024, E = 1024;
  int f = blockIdx.x;
  __shared__ float sh[8192];
  __shared__ float ps[4], pq[4], sc[2];

  const float* xf = x + (size_t)f * E;
  float ls = 0.f, lq = 0.f;
  for (int i = threadIdx.x; i < 8192; i += 256) {
    int b = i >> 10, e = i & 1023;
    float v = xf[(size_t)b * F * E + e];
    sh[i] = v;
    ls += v;
    lq += v * v;
  }
  #pragma unroll
  for (int o = 32; o > 0; o >>= 1) {
    ls += __shfl_down(ls, o, 64);
    lq += __shfl_down(lq, o, 64);
  }
  int w = threadIdx.x >> 6;
  if ((threadIdx.x & 63) == 0) { ps[w] = ls; pq[w] = lq; }
  __syncthreads();
  if (threadIdx.x == 0) {
    float s = ps[0] + ps[1] + ps[2] + ps[3];
    float q = pq[0] + pq[1] + pq[2] + pq[3];
    float mean = s * (1.f / 8192.f);
    float var = q * (1.f / 8192.f) - mean * mean;
    float scale = gamma[f] * rsqrtf(var + 1e-5f);
    sc[0] = scale;
    sc[1] = beta[f] - mean * scale;
  }
  __syncthreads();
  float scale = sc[0], shift = sc[1];
  for (int i = threadIdx.x; i < 8192; i += 256) {
    int b = i >> 10, e = i & 1023;
    xn[((size_t)(b * F + f)) * E + e] = f2bf(sh[i] * scale + shift);
  }
}

// ---------------------------------------------------------------------------
// Kernel 2: W_qkv f32 -> bf16
// ---------------------------------------------------------------------------
__global__ __launch_bounds__(256) void wconv_kernel(
    const float* __restrict__ W, u16* __restrict__ Wb) {
  const int total = 3072 * 1024 / 4;
  for (int i = blockIdx.x * 256 + threadIdx.x; i < total; i += gridDim.x * 256) {
    float4 v = ((const float4*)W)[i];
    ushort4 o;
    o.x = f2bf(v.x); o.y = f2bf(v.y); o.z = f2bf(v.z); o.w = f2bf(v.w);
    ((ushort4*)Wb)[i] = o;
  }
}

// ---------------------------------------------------------------------------
// Kernel 3: GEMM (m97 structure + R15 swizzle) with FUSED V-transpose epilogue.
//  C[m][n] = sum_k A[m][k]*Bw[n][k] + bias[n]
//  Output routing (vt_kernel eliminated):
//   - each 16-col fragment is wave-uniformly Q/K or V (boundaries 192k and
//     192k+128 are multiples of 16);
//   - Q/K cols -> qkv[m][col] as before (attn reads stride 3072);
//   - V cols   -> Vt[b*16+h][d][perm(f)] with the baked key permutation,
//     position formula validated in R10's passing run:
//       fbase = (m0&1023)+wr*64+mi*16+g*4
//       pos   = (fbase&~31) + (g>>1)*16 + (g&1)*8 + (mi&1)*4   (8B store)
// ---------------------------------------------------------------------------
__global__ __launch_bounds__(256) void gemm_qkv_kernel(
    const u16* __restrict__ A, const u16* __restrict__ Bw,
    const float* __restrict__ bias, u16* __restrict__ C,
    u16* __restrict__ Vt) {
  const int K = 1024, N = 3072;
  __shared__ u16 As[128 * 32];
  __shared__ u16 Bs[128 * 32];

  int m0 = blockIdx.x * 128, n0 = blockIdx.y * 128;
  int t = threadIdx.x, lane = t & 63, w = t >> 6;
  int wr = w >> 1, wc = w & 1;
  int r = lane & 15, g = lane >> 4;

  int srow = t >> 2;
  int scol = ((t & 3) ^ ((srow >> 1) & 3)) * 8;   // pre-swizzled source chunk
  const u16* gA  = A  + (size_t)(m0 + srow) * K + scol;
  const u16* gA2 = A  + (size_t)(m0 + 64 + srow) * K + scol;
  const u16* gB  = Bw + (size_t)(n0 + srow) * K + scol;
  const u16* gB2 = Bw + (size_t)(n0 + 64 + srow) * K + scol;
  u16* lA  = As + t * 8;
  u16* lA2 = As + 2048 + t * 8;
  u16* lB  = Bs + t * 8;
  u16* lB2 = Bs + 2048 + t * 8;

  f32x4 acc[4][4] = {};

  // fragment read: actual chunk g lives at position g ^ ((r>>1)&3)
  int rc = (g ^ ((r >> 1) & 3)) * 8;
  const u16* pA = As + (size_t)(wr * 64 + r) * 32 + rc;
  const u16* pB = Bs + (size_t)(wc * 64 + r) * 32 + rc;

  for (int k0 = 0; k0 < K; k0 += 32) {
    __builtin_amdgcn_global_load_lds((gas_ptr)gA,  (las_ptr)lA,  16, 0, 0);
    __builtin_amdgcn_global_load_lds((gas_ptr)gA2, (las_ptr)lA2, 16, 0, 0);
    __builtin_amdgcn_global_load_lds((gas_ptr)gB,  (las_ptr)lB,  16, 0, 0);
    __builtin_amdgcn_global_load_lds((gas_ptr)gB2, (las_ptr)lB2, 16, 0, 0);
    gA += 32; gA2 += 32; gB += 32; gB2 += 32;
    __syncthreads();

    bf16x8 af[4], bfr[4];
    #pragma unroll
    for (int mi = 0; mi < 4; ++mi)
      af[mi] = __builtin_bit_cast(bf16x8, *(const int4*)(pA + mi * 512));
    #pragma unroll
    for (int ni = 0; ni < 4; ++ni)
      bfr[ni] = __builtin_bit_cast(bf16x8, *(const int4*)(pB + ni * 512));
    #pragma unroll
    for (int mi = 0; mi < 4; ++mi)
      #pragma unroll
      for (int ni = 0; ni < 4; ++ni)
        acc[mi][ni] = __builtin_amdgcn_mfma_f32_16x16x32_bf16(af[mi], bfr[ni], acc[mi][ni], 0, 0, 0);
    __syncthreads();
  }

  // ---- epilogue: Q/K -> qkv ; V -> Vt (baked permutation, R10-validated)
  int b_ = m0 >> 10;
  #pragma unroll
  for (int ni = 0; ni < 4; ++ni) {
    int colb = n0 + wc * 64 + ni * 16;        // wave-uniform fragment base
    int col = colb + r;
    float bv = bias[col];
    int h_ = colb / 192;
    int rr = colb - h_ * 192;                  // 0..176, multiple of 16
    if (rr >= 128) {
      // V fragment: d = rr-128+r, write transposed+permuted
      int d_ = rr - 128 + r;
      u16* vtd = Vt + (size_t)(b_ * 16 + h_) * 65536 + (size_t)d_ * 1024;
      #pragma unroll
      for (int mi = 0; mi < 4; ++mi) {
        int fbase = (m0 & 1023) + wr * 64 + mi * 16 + g * 4;
        int pos = (fbase & ~31) + ((g >> 1) * 16) + ((g & 1) * 8) + ((mi & 1) * 4);
        uint2 st;
        st.x = cvtpk(acc[mi][ni][0] + bv, acc[mi][ni][1] + bv);
        st.y = cvtpk(acc[mi][ni][2] + bv, acc[mi][ni][3] + bv);
        *(uint2*)(vtd + pos) = st;
      }
    } else {
      #pragma unroll
      for (int mi = 0; mi < 4; ++mi) {
        int row = m0 + wr * 64 + mi * 16 + g * 4;
        #pragma unroll
        for (int j = 0; j < 4; ++j)
          C[(size_t)(row + j) * N + col] = f2bf(acc[mi][ni][j] + bv);
      }
    }
  }
}

// ---------------------------------------------------------------------------
// Kernel 4: flash attention v9 (R12 winner, 69.6us) — raw v_exp, full unroll,
// triple-buffered K/V, counted-vmcnt pipeline, seeded-C softmax.
// ---------------------------------------------------------------------------
__global__ __launch_bounds__(256) void attn_kernel(
    const u16* __restrict__ qkv, const u16* __restrict__ Vt,
    float* __restrict__ out) {
  const int F = 1024, NQ = 3072;
  int bid = blockIdx.x;           // 2048 blocks
  int xcd = bid & 7;
  int li  = bid >> 3;             // 0..255
  int bh  = ((li >> 4) << 3) | xcd;
  int ql  = li & 15;
  int w   = threadIdx.x >> 6;
  int lane = threadIdx.x & 63;
  int q = lane & 15, g = lane >> 4;
  int qs = q & 7;
  int q0 = ql * 64 + w * 16;
  int b = bh >> 4, h = bh & 15;

  const u16* base = qkv + (size_t)b * F * NQ + h * 192;
  const u16* VtBH = Vt + (size_t)bh * 65536;

  __shared__ u16 S[24576];

  int i8 = lane >> 3;
  int ic = lane & 7;

  const float qscale = 0.125f * 1.4426950408889634f;
  bf16x8 Qf0, Qf1;
  {
    const u16* qp = base + (size_t)(q0 + q) * NQ + g * 8;
    union { int4 v; u16 u[8]; } uu0, uu1;
    uu0.v = *(const int4*)(qp);
    uu1.v = *(const int4*)(qp + 32);
    union { u32 w4[4]; bf16x8 v; } p0, p1;
    #pragma unroll
    for (int j = 0; j < 4; ++j) {
      p0.w4[j] = cvtpk(bf2f(uu0.u[2 * j]) * qscale, bf2f(uu0.u[2 * j + 1]) * qscale);
      p1.w4[j] = cvtpk(bf2f(uu1.u[2 * j]) * qscale, bf2f(uu1.u[2 * j + 1]) * qscale);
    }
    Qf0 = p0.v; Qf1 = p1.v;
  }

  f32x4 acc[4] = {};
  float m = 0.0f, lsum = 0.f;

  #define STAGE(buf, kt)                                                       \
    do {                                                                       \
      int kb_ = (kt) * 64;                                                     \
      _Pragma("unroll")                                                        \
      for (int rr = 0; rr < 2; ++rr) {                                         \
        int r_ = rr * 32 + w * 8 + i8;                                         \
        int sc_ = (ic ^ (r_ & 7)) * 8;                                         \
        const u16* ks_ = base + (size_t)(kb_ + r_) * NQ + 64 + sc_;            \
        const u16* vs_ = VtBH + (size_t)r_ * 1024 + kb_ + sc_;                 \
        __builtin_amdgcn_global_load_lds((gas_ptr)ks_,                         \
            (las_ptr)&S[(buf) * 4096 + (rr * 32 + w * 8) * 64], 16, 0, 0);     \
        __builtin_amdgcn_global_load_lds((gas_ptr)vs_,                         \
            (las_ptr)&S[12288 + (buf) * 4096 + (rr * 32 + w * 8) * 64], 16, 0, 0);\
      }                                                                        \
    } while (0)

  __builtin_amdgcn_sched_barrier(0);
  STAGE(0, 0);
  STAGE(1, 1);
  asm volatile("s_waitcnt vmcnt(4)" ::: "memory");
  __builtin_amdgcn_s_barrier();
  __builtin_amdgcn_sched_barrier(0);

  #pragma unroll
  for (int kt = 0; kt < 16; ++kt) {
    const int cur = kt % 3;
    const int stg = (kt + 2) % 3;
    if (kt < 14) STAGE(stg, kt + 2);

    const u16* Kb = &S[cur * 4096];
    const u16* Vb = &S[12288 + cur * 4096];

    f32x4 s[4];
    f32x4 seed = {-m, -m, -m, -m};
    __builtin_amdgcn_s_setprio(1);
    #pragma unroll
    for (int ks = 0; ks < 4; ++ks) {
      int row = ks * 16 + q;
      int4 k0 = *(const int4*)&Kb[row * 64 + ((g ^ qs) * 8)];
      int4 k1 = *(const int4*)&Kb[row * 64 + (((4 + g) ^ qs) * 8)];
      f32x4 sv = seed;
      sv = __builtin_amdgcn_mfma_f32_16x16x32_bf16(__builtin_bit_cast(bf16x8, k0), Qf0, sv, 0, 0, 0);
      sv = __builtin_amdgcn_mfma_f32_16x16x32_bf16(__builtin_bit_cast(bf16x8, k1), Qf1, sv, 0, 0, 0);
      s[ks] = sv;
    }
    __builtin_amdgcn_s_setprio(0);

    float a0 = fmaxf(fmaxf(s[0][0], s[0][1]), s[0][2]);
    float a1 = fmaxf(fmaxf(s[0][3], s[1][0]), s[1][1]);
    float a2 = fmaxf(fmaxf(s[1][2], s[1][3]), s[2][0]);
    float a3 = fmaxf(fmaxf(s[2][1], s[2][2]), s[2][3]);
    float a4 = fmaxf(fmaxf(s[3][0], s[3][1]), s[3][2]);
    float tmx = fmaxf(fmaxf(fmaxf(a0, a1), a2), fmaxf(fmaxf(a3, a4), s[3][3]));

    float p[16];
    if (__builtin_expect(__any(tmx > 8.0f), 0)) {
      float tr = fmaxf(tmx, __shfl_xor(tmx, 16, 64));
      tr = fmaxf(tr, __shfl_xor(tr, 32, 64));
      float dm = fmaxf(tr, 0.f);
      float alpha = fexp2(-dm);
      lsum *= alpha;
      acc[0] *= alpha; acc[1] *= alpha; acc[2] *= alpha; acc[3] *= alpha;
      m += dm;
      #pragma unroll
      for (int ks = 0; ks < 4; ++ks) {
        p[ks * 4 + 0] = fexp2(s[ks][0] - dm);
        p[ks * 4 + 1] = fexp2(s[ks][1] - dm);
        p[ks * 4 + 2] = fexp2(s[ks][2] - dm);
        p[ks * 4 + 3] = fexp2(s[ks][3] - dm);
      }
    } else {
      #pragma unroll
      for (int ks = 0; ks < 4; ++ks) {
        p[ks * 4 + 0] = fexp2(s[ks][0]);
        p[ks * 4 + 1] = fexp2(s[ks][1]);
        p[ks * 4 + 2] = fexp2(s[ks][2]);
        p[ks * 4 + 3] = fexp2(s[ks][3]);
      }
    }
    float q01 = p[0] + p[1],   q23 = p[2] + p[3];
    float q45 = p[4] + p[5],   q67 = p[6] + p[7];
    float q89 = p[8] + p[9],   qab = p[10] + p[11];
    float qcd = p[12] + p[13], qef = p[14] + p[15];
    lsum += ((q01 + q23) + (q45 + q67)) + ((q89 + qab) + (qcd + qef));

    union { u32 w4[4]; bf16x8 v; } pb0, pb1;
    pb0.w4[0] = cvtpk(p[0], p[1]);   pb0.w4[1] = cvtpk(p[2], p[3]);
    pb0.w4[2] = cvtpk(p[4], p[5]);   pb0.w4[3] = cvtpk(p[6], p[7]);
    pb1.w4[0] = cvtpk(p[8], p[9]);   pb1.w4[1] = cvtpk(p[10], p[11]);
    pb1.w4[2] = cvtpk(p[12], p[13]); pb1.w4[3] = cvtpk(p[14], p[15]);

    __builtin_amdgcn_s_setprio(1);
    #pragma unroll
    for (int dt = 0; dt < 4; ++dt) {
      int row = dt * 16 + q;
      int4 v0 = *(const int4*)&Vb[row * 64 + ((g ^ qs) * 8)];
      int4 v1 = *(const int4*)&Vb[row * 64 + (((4 + g) ^ qs) * 8)];
      acc[dt] = __builtin_amdgcn_mfma_f32_16x16x32_bf16(__builtin_bit_cast(bf16x8, v0), pb0.v, acc[dt], 0, 0, 0);
      acc[dt] = __builtin_amdgcn_mfma_f32_16x16x32_bf16(__builtin_bit_cast(bf16x8, v1), pb1.v, acc[dt], 0, 0, 0);
    }
    __builtin_amdgcn_s_setprio(0);

    if (kt < 14) {
      asm volatile("s_waitcnt vmcnt(4)" ::: "memory");
    } else {
      asm volatile("s_waitcnt vmcnt(0)" ::: "memory");
    }
    __builtin_amdgcn_s_barrier();
    __builtin_amdgcn_sched_barrier(0);
  }
  #undef STAGE

  lsum += __shfl_xor(lsum, 16, 64);
  lsum += __shfl_xor(lsum, 32, 64);
  float inv = 1.0f / lsum;

  float* oT = (float*)S + (size_t)w * 1088;
  #pragma unroll
  for (int dt = 0; dt < 4; ++dt) {
    oT[(dt * 16 + g * 4 + 0) * 17 + q] = acc[dt][0] * inv;
    oT[(dt * 16 + g * 4 + 1) * 17 + q] = acc[dt][1] * inv;
    oT[(dt * 16 + g * 4 + 2) * 17 + q] = acc[dt][2] * inv;
    oT[(dt * 16 + g * 4 + 3) * 17 + q] = acc[dt][3] * inv;
  }
  asm volatile("s_waitcnt lgkmcnt(0)" ::: "memory");
  int oq = lane >> 2, dc = (lane & 3) * 16;
  float* orow = out + (size_t)(b * F + q0 + oq) * 1024 + h * 64 + dc;
  #pragma unroll
  for (int c4 = 0; c4 < 4; ++c4) {
    float4 v;
    v.x = oT[(dc + c4 * 4 + 0) * 17 + oq];
    v.y = oT[(dc + c4 * 4 + 1) * 17 + oq];
    v.z = oT[(dc + c4 * 4 + 2) * 17 + oq];
    v.w = oT[(dc + c4 * 4 + 3) * 17 + oq];
    *(float4*)(orow + c4 * 4) = v;
  }
}

// ---------------------------------------------------------------------------
extern "C" void kernel_launch(void* const* d_in, const int* in_sizes, int n_in,
                              void* d_out, int out_size, void* d_ws, size_t ws_size,
                              hipStream_t stream) {
  const float* x     = (const float*)d_in[0];
  const float* gamma = (const float*)d_in[1];
  const float* beta  = (const float*)d_in[2];
  const float* W     = (const float*)d_in[3];
  const float* bias  = (const float*)d_in[4];
  float* out = (float*)d_out;

  char* ws = (char*)d_ws;
  u16* xn  = (u16*)ws;                                   // 16 MB
  u16* Wb  = (u16*)(ws + (size_t)16 * 1024 * 1024);      //  6 MB
  u16* qkv = (u16*)(ws + (size_t)22 * 1024 * 1024);      // 48 MB
  u16* Vt  = (u16*)(ws + (size_t)70 * 1024 * 1024);      // 16 MB

  bn_norm_kernel<<<1024, 256, 0, stream>>>(x, gamma, beta, xn);
  wconv_kernel<<<768, 256, 0, stream>>>(W, Wb);
  gemm_qkv_kernel<<<dim3(64, 24), 256, 0, stream>>>(xn, Wb, bias, qkv, Vt);
  attn_kernel<<<2048, 256, 0, stream>>>(qkv, Vt, out);
}